// Round 3
// baseline (693.457 us; speedup 1.0000x reference)
//
#include <hip/hip_runtime.h>
#include <hip/hip_bf16.h>
#include <math.h>

// Problem constants (B=32, T=256, V=32000, D=512)
#define R   8192    // B*T rows
#define TT  256
#define D   512
#define V   32000
#define G3  1536    // 3*D (z|f|o)

typedef __attribute__((ext_vector_type(8))) short bf16x8;
typedef __attribute__((ext_vector_type(4))) float f32x4;

__device__ __forceinline__ float bf2f(ushort u) {
  union { unsigned int i; float f; } x; x.i = ((unsigned int)u) << 16; return x.f;
}
__device__ __forceinline__ ushort f2bf(float f) {   // RNE
  union { float f; unsigned int i; } x; x.f = f;
  unsigned int r = x.i + 0x7fffu + ((x.i >> 16) & 1u);
  return (ushort)(r >> 16);
}

__device__ __forceinline__ void gload16(const void* g, void* l) {
  __builtin_amdgcn_global_load_lds((const __attribute__((address_space(1))) void*)g,
                                   (__attribute__((address_space(3))) void*)l, 16, 0, 0);
}

// ---------------- embedding gather -> XA bf16 [R][1024] = [x_prev | x] ----------------
__global__ __launch_bounds__(256) void embed_kernel(const int* __restrict__ tok,
                                                    const float4* __restrict__ emb,
                                                    ushort4* __restrict__ XA) {
  int idx = blockIdx.x * 256 + threadIdx.x;   // over R*128 float4s
  int r = idx >> 7, d4 = idx & 127;
  float4 v = emb[(size_t)tok[r] * 128 + d4];
  ushort4 h; h.x = f2bf(v.x); h.y = f2bf(v.y); h.z = f2bf(v.z); h.w = f2bf(v.w);
  XA[(size_t)r * 256 + 128 + d4] = h;                       // x part
  int t = r & (TT - 1);
  if (t < TT - 1) XA[(size_t)(r + 1) * 256 + d4] = h;       // next row's x_prev
  if (t == 0) { ushort4 z4; z4.x=z4.y=z4.z=z4.w=0; XA[(size_t)r * 256 + d4] = z4; }
}

// ---------------- weight transpose+convert: WcatT[1536][1024] bf16 ----------------
__global__ __launch_bounds__(256) void wconv(const float* __restrict__ Wz,
                                             const float* __restrict__ Wf,
                                             const float* __restrict__ Wo,
                                             ushort* __restrict__ WT) {
  __shared__ float tile[64][65];
  int z = blockIdx.z, g = z >> 1, i = z & 1;
  const float* src = (g == 0) ? Wz : (g == 1 ? Wf : Wo);
  src += (size_t)i * D * D;
  int d0 = blockIdx.x * 64, e0 = blockIdx.y * 64;
  int t = threadIdx.x, c = t & 63, rq = t >> 6;
#pragma unroll
  for (int p = 0; p < 16; ++p) {
    int dd = p * 4 + rq;
    tile[dd][c] = src[(size_t)(d0 + dd) * D + e0 + c];
  }
  __syncthreads();
#pragma unroll
  for (int p = 0; p < 16; ++p) {
    int ee = p * 4 + rq;
    WT[(size_t)(g * D + e0 + ee) * 1024 + i * D + d0 + c] = f2bf(tile[c][ee]);
  }
}

// ---------------- softmax weight transpose+convert: SWT[32000][512] bf16 ----------------
__global__ __launch_bounds__(256) void swconv(const float* __restrict__ SW,
                                              ushort* __restrict__ SWT) {
  __shared__ float tile[64][65];
  int k0 = blockIdx.x * 64, n0 = blockIdx.y * 64;
  int t = threadIdx.x, c = t & 63, rq = t >> 6;
#pragma unroll
  for (int p = 0; p < 16; ++p) {
    int kk = p * 4 + rq;
    tile[kk][c] = SW[(size_t)(k0 + kk) * V + n0 + c];
  }
  __syncthreads();
#pragma unroll
  for (int p = 0; p < 16; ++p) {
    int nn = p * 4 + rq;
    SWT[(size_t)(n0 + nn) * D + k0 + c] = f2bf(tile[c][nn]);
  }
}

// ---------------- bias concat ----------------
__global__ void bcat_kernel(const float* bz0, const float* bf0, const float* bo0,
                            const float* bz1, const float* bf1, const float* bo1,
                            float* BC0, float* BC1) {
  int idx = blockIdx.x * 256 + threadIdx.x;
  if (idx >= 2 * G3) return;
  int layer = idx / G3, rem = idx % G3, g = rem >> 9, e = rem & 511;
  const float* s = (layer == 0) ? (g == 0 ? bz0 : (g == 1 ? bf0 : bo0))
                                : (g == 0 ? bz1 : (g == 1 ? bf1 : bo1));
  (layer == 0 ? BC0 : BC1)[rem] = s[e];
}

// ---------------- bf16 MFMA GEMM core (double-buffered, stage-ahead) ----------------
// C[128x128] per 256-thread block (4 waves, 2x2 of 64x64 wave tiles, 4x4 frags).
// A row-major [M][K], B row-major-transposed [N][K] (both K-contiguous, bf16).
// LDS: 2 buffers x (As 16KB + Bs 16KB) = 64KB. Linear dest; global source
// pre-swizzled (slot=(lane&7)^lrow); reads use sl=(ks*4+hi)^(row&7)  [rule #21].
// T3-minimum pipeline: STAGE(kt+1) issued BEFORE computing kt; the single
// __syncthreads per K-step (implicit vmcnt(0)+lgkmcnt(0) drain) lands it.
__device__ __forceinline__ void stage_tile(const ushort* ga0, const ushort* gb0,
                                           int ldA, int ldB, int koff,
                                           char* As_, char* Bs_, int w) {
#pragma unroll
  for (int i = 0; i < 4; ++i) {
    int chunk = w * 4 + i;
    gload16(ga0 + (size_t)i * 8 * ldA + koff, As_ + chunk * 1024);
    gload16(gb0 + (size_t)i * 8 * ldB + koff, Bs_ + chunk * 1024);
  }
}

template<int KTOT, int LDA, int LDB>
__device__ __forceinline__ void gemm_tile(const ushort* __restrict__ A,
                                          const ushort* __restrict__ B,
                                          int row0, int col0,
                                          char* lds, f32x4 acc[4][4]) {
  const int t = threadIdx.x, lane = t & 63, w = t >> 6;
  const int wm = w >> 1, wn = w & 1;
  const int lrow = lane >> 3;            // row within 8-row chunk
  const int slot = (lane & 7) ^ lrow;    // inverse-swizzled source 16B slot
  const int lo = lane & 15, hi = lane >> 4;
  constexpr int NT = KTOT / 64;

  const ushort* ga0 = A + (size_t)(row0 + w * 32 + lrow) * LDA + slot * 8;
  const ushort* gb0 = B + (size_t)(col0 + w * 32 + lrow) * LDB + slot * 8;

  stage_tile(ga0, gb0, LDA, LDB, 0, lds, lds + 16384, w);
  __syncthreads();                       // drains vmcnt(0): tile 0 landed
  int cur = 0;
#pragma unroll 1
  for (int kt = 0; kt < NT; ++kt) {
    // issue next tile's stage into the other buffer (overlaps with compute)
    if (kt + 1 < NT)
      stage_tile(ga0, gb0, LDA, LDB, (kt + 1) * 64,
                 lds + (cur ^ 1) * 32768, lds + (cur ^ 1) * 32768 + 16384, w);
    const char* As = lds + cur * 32768;
    const char* Bs = lds + cur * 32768 + 16384;
#pragma unroll
    for (int ks = 0; ks < 2; ++ks) {
      bf16x8 av[4], bv[4];
#pragma unroll
      for (int mi = 0; mi < 4; ++mi) {
        int row = wm * 64 + mi * 16 + lo;
        int sl  = (ks * 4 + hi) ^ (row & 7);
        av[mi] = *(const bf16x8*)(As + row * 128 + sl * 16);
      }
#pragma unroll
      for (int ni = 0; ni < 4; ++ni) {
        int row = wn * 64 + ni * 16 + lo;
        int sl  = (ks * 4 + hi) ^ (row & 7);
        bv[ni] = *(const bf16x8*)(Bs + row * 128 + sl * 16);
      }
#pragma unroll
      for (int mi = 0; mi < 4; ++mi)
#pragma unroll
        for (int ni = 0; ni < 4; ++ni)
          acc[mi][ni] = __builtin_amdgcn_mfma_f32_16x16x32_bf16(av[mi], bv[ni], acc[mi][ni], 0, 0, 0);
    }
    __syncthreads();                     // drains vmcnt(0): tile kt+1 landed; LDS reads done
    cur ^= 1;
  }
}

// ---------------- QRNN pre-activation GEMM (8192x1536x1024) ----------------
__global__ __launch_bounds__(256) void gemm_pre(const ushort* __restrict__ A,
                                                const ushort* __restrict__ B,
                                                const float* __restrict__ bcat,
                                                ushort* __restrict__ PRE) {
  __shared__ char lds[65536];
  f32x4 acc[4][4];
#pragma unroll
  for (int i = 0; i < 4; ++i)
#pragma unroll
    for (int j = 0; j < 4; ++j) { f32x4 z = {0.f,0.f,0.f,0.f}; acc[i][j] = z; }
  const int row0 = blockIdx.x * 128, col0 = blockIdx.y * 128;
  gemm_tile<1024,1024,1024>(A, B, row0, col0, lds, acc);
  const int lane = threadIdx.x & 63, w = threadIdx.x >> 6;
  const int wm = w >> 1, wn = w & 1, lo = lane & 15, hi = lane >> 4;
#pragma unroll
  for (int ni = 0; ni < 4; ++ni) {
    int col = col0 + wn * 64 + ni * 16 + lo;
    float bb = bcat[col];
#pragma unroll
    for (int mi = 0; mi < 4; ++mi) {
      int r0 = row0 + wm * 64 + mi * 16 + hi * 4;
#pragma unroll
      for (int j = 0; j < 4; ++j)
        PRE[(size_t)(r0 + j) * G3 + col] = f2bf(acc[mi][ni][j] + bb);
    }
  }
}

// ---------------- logits GEMM (8192x32000x512) + fused exp-sum + target capture ----------------
__global__ __launch_bounds__(256) void gemm_lse(const ushort* __restrict__ A,
                                                const ushort* __restrict__ B,
                                                const float* __restrict__ SB,
                                                const int* __restrict__ tgt,
                                                float* __restrict__ SUM,
                                                float* __restrict__ TGL) {
  __shared__ char lds[65536];
  f32x4 acc[4][4];
#pragma unroll
  for (int i = 0; i < 4; ++i)
#pragma unroll
    for (int j = 0; j < 4; ++j) { f32x4 z = {0.f,0.f,0.f,0.f}; acc[i][j] = z; }
  const int row0 = blockIdx.x * 128, col0 = blockIdx.y * 128;
  gemm_tile<512,512,512>(A, B, row0, col0, lds, acc);
  const int lane = threadIdx.x & 63, w = threadIdx.x >> 6;
  const int wm = w >> 1, wn = w & 1, lo = lane & 15, hi = lane >> 4;
#pragma unroll
  for (int mi = 0; mi < 4; ++mi) {
    int r0 = row0 + wm * 64 + mi * 16 + hi * 4;
    int tg[4];
    float s[4] = {0.f, 0.f, 0.f, 0.f};
#pragma unroll
    for (int j = 0; j < 4; ++j) tg[j] = tgt[r0 + j];
#pragma unroll
    for (int ni = 0; ni < 4; ++ni) {
      int col = col0 + wn * 64 + ni * 16 + lo;
      float bb = SB[col];
#pragma unroll
      for (int j = 0; j < 4; ++j) {
        float v = acc[mi][ni][j] + bb;
        if (col == tg[j]) TGL[r0 + j] = v;   // exactly one writer per row
        s[j] += __expf(v);
      }
    }
#pragma unroll
    for (int m = 1; m < 16; m <<= 1) {
#pragma unroll
      for (int j = 0; j < 4; ++j) s[j] += __shfl_xor(s[j], m, 64);
    }
    if (lo == 0) {
#pragma unroll
      for (int j = 0; j < 4; ++j) atomicAdd(&SUM[r0 + j], s[j]);
    }
  }
}

// ---------------- fo-pool scan (bf16 in, bf16 out in next-GEMM A layout) ----------------
// 256 blocks x 64 threads: one wave per (b, d-chunk of 64) -> all 256 CUs busy.
// mode 0: OUT = YA [R][1024]: [r][512+d]=h(r), [r+1][d]=h(r) (t<255), [r][d]=0 (t==0)
// mode 1: OUT = H2 [R][512]
__global__ __launch_bounds__(64) void scan_kernel(const ushort* __restrict__ PRE,
                                                  ushort* __restrict__ OUT, int mode) {
  int idx = blockIdx.x * 64 + threadIdx.x;    // 32*512
  int b = idx >> 9, d = idx & 511;
  const ushort* p = PRE + (size_t)b * TT * G3 + d;
  float c = 0.f;
  for (int t0 = 0; t0 < TT; t0 += 8) {
    float pz[8], pf[8], po[8];
#pragma unroll
    for (int i = 0; i < 8; ++i) {
      const ushort* q = p + (size_t)(t0 + i) * G3;
      pz[i] = bf2f(q[0]); pf[i] = bf2f(q[512]); po[i] = bf2f(q[1024]);
    }
#pragma unroll
    for (int i = 0; i < 8; ++i) {
      float z = 2.f / (1.f + __expf(-2.f * pz[i])) - 1.f;
      float f = 1.f / (1.f + __expf(-pf[i]));
      float o = 1.f / (1.f + __expf(-po[i]));
      c = f * c + (1.f - f) * z;
      float h = o * c;
      int tt = t0 + i;
      size_t r = (size_t)b * TT + tt;
      ushort hb = f2bf(h);
      if (mode == 0) {
        OUT[r * 1024 + 512 + d] = hb;
        if (tt < TT - 1) OUT[(r + 1) * 1024 + d] = hb;
        if (tt == 0)     OUT[r * 1024 + d] = 0;
      } else {
        OUT[r * 512 + d] = hb;
      }
    }
  }
}

// ---------------- helpers ----------------
__global__ void zero_kernel(float* __restrict__ p, int n) {
  int i = blockIdx.x * 256 + threadIdx.x;
  if (i < n) p[i] = 0.f;
}

__global__ __launch_bounds__(256) void cost_kernel(const float* __restrict__ sumexp,
                                                   const float* __restrict__ tgl,
                                                   float* __restrict__ out) {
  int t = threadIdx.x;
  float s = 0.f;
  for (int r = t; r < R; r += 256) s += logf(sumexp[r]) - tgl[r];
#pragma unroll
  for (int m = 1; m < 64; m <<= 1) s += __shfl_xor(s, m, 64);
  __shared__ float red[4];
  int wave = t >> 6, lane = t & 63;
  if (lane == 0) red[wave] = s;
  __syncthreads();
  if (t == 0) out[0] = (red[0] + red[1] + red[2] + red[3]) / (float)R;
}

extern "C" void kernel_launch(void* const* d_in, const int* in_sizes, int n_in,
                              void* d_out, int out_size, void* d_ws, size_t ws_size,
                              hipStream_t stream) {
  const int*   tok = (const int*)d_in[0];
  const int*   tgt = (const int*)d_in[1];
  const float* emb = (const float*)d_in[2];
  const float* Wz0 = (const float*)d_in[3];  const float* bz0 = (const float*)d_in[4];
  const float* Wf0 = (const float*)d_in[5];  const float* bf0 = (const float*)d_in[6];
  const float* Wo0 = (const float*)d_in[7];  const float* bo0 = (const float*)d_in[8];
  const float* Wz1 = (const float*)d_in[9];  const float* bz1 = (const float*)d_in[10];
  const float* Wf1 = (const float*)d_in[11]; const float* bf1 = (const float*)d_in[12];
  const float* Wo1 = (const float*)d_in[13]; const float* bo1 = (const float*)d_in[14];
  const float* SW  = (const float*)d_in[15]; const float* SB  = (const float*)d_in[16];
  float* out = (float*)d_out;

  // workspace layout (bytes), total ~70.1 MB:
  char* base = (char*)d_ws;
  ushort* XA  = (ushort*)(base);               // 16,777,216  [R][1024] bf16
  ushort* YA  = (ushort*)(base + 16777216);    // 16,777,216  [R][1024] bf16
  ushort* PRE = (ushort*)(base + 33554432);    // 25,165,824  [R][1536] bf16
  ushort* H2  = (ushort*)(base + 58720256);    //  8,388,608  [R][512]  bf16
  ushort* WT0 = (ushort*)(base + 67108864);    //  3,145,728  [1536][1024] bf16
  ushort* WT1 = (ushort*)(base + 70254592);    //  3,145,728
  float*  BC0 = (float*)(base + 73400320);     //  6,144
  float*  BC1 = (float*)(base + 73406464);     //  6,144
  float*  SUM = (float*)(base + 73412608);     //  32,768
  float*  TGL = (float*)(base + 73445376);     //  32,768
  ushort* SWT = (ushort*)(base);               // alias over XA+YA (32,768,000 <= 33,554,432)

  embed_kernel<<<R * 128 / 256, 256, 0, stream>>>(tok, (const float4*)emb, (ushort4*)XA);
  wconv<<<dim3(8, 8, 6), 256, 0, stream>>>(Wz0, Wf0, Wo0, WT0);
  wconv<<<dim3(8, 8, 6), 256, 0, stream>>>(Wz1, Wf1, Wo1, WT1);
  bcat_kernel<<<12, 256, 0, stream>>>(bz0, bf0, bo0, bz1, bf1, bo1, BC0, BC1);

  gemm_pre<<<dim3(64, 12), 256, 0, stream>>>(XA, WT0, BC0, PRE);
  scan_kernel<<<256, 64, 0, stream>>>(PRE, YA, 0);
  gemm_pre<<<dim3(64, 12), 256, 0, stream>>>(YA, WT1, BC1, PRE);
  scan_kernel<<<256, 64, 0, stream>>>(PRE, H2, 1);

  // SWT aliases XA/YA — both dead after the second gemm_pre
  swconv<<<dim3(8, 500), 256, 0, stream>>>(SW, SWT);
  zero_kernel<<<32, 256, 0, stream>>>(SUM, R);
  gemm_lse<<<dim3(64, 250), 256, 0, stream>>>(H2, SWT, SB, tgt, SUM, TGL);
  cost_kernel<<<1, 256, 0, stream>>>(SUM, TGL, out);
}

// Round 4
// 692.788 us; speedup vs baseline: 1.0010x; 1.0010x over previous
//
#include <hip/hip_runtime.h>
#include <hip/hip_bf16.h>
#include <math.h>

// Problem constants (B=32, T=256, V=32000, D=512)
#define R   8192    // B*T rows
#define TT  256
#define D   512
#define V   32000
#define G3  1536    // 3*D (z|f|o)

typedef __attribute__((ext_vector_type(8))) short bf16x8;
typedef __attribute__((ext_vector_type(4))) float f32x4;

__device__ __forceinline__ float bf2f(ushort u) {
  union { unsigned int i; float f; } x; x.i = ((unsigned int)u) << 16; return x.f;
}
__device__ __forceinline__ ushort f2bf(float f) {   // RNE
  union { float f; unsigned int i; } x; x.f = f;
  unsigned int r = x.i + 0x7fffu + ((x.i >> 16) & 1u);
  return (ushort)(r >> 16);
}

__device__ __forceinline__ void gload16(const void* g, void* l) {
  __builtin_amdgcn_global_load_lds((const __attribute__((address_space(1))) void*)g,
                                   (__attribute__((address_space(3))) void*)l, 16, 0, 0);
}

// ---------------- embedding gather -> XA bf16 [R][1024] = [x_prev | x] ----------------
__global__ __launch_bounds__(256) void embed_kernel(const int* __restrict__ tok,
                                                    const float4* __restrict__ emb,
                                                    ushort4* __restrict__ XA) {
  int idx = blockIdx.x * 256 + threadIdx.x;   // over R*128 float4s
  int r = idx >> 7, d4 = idx & 127;
  float4 v = emb[(size_t)tok[r] * 128 + d4];
  ushort4 h; h.x = f2bf(v.x); h.y = f2bf(v.y); h.z = f2bf(v.z); h.w = f2bf(v.w);
  XA[(size_t)r * 256 + 128 + d4] = h;                       // x part
  int t = r & (TT - 1);
  if (t < TT - 1) XA[(size_t)(r + 1) * 256 + d4] = h;       // next row's x_prev
  if (t == 0) { ushort4 z4; z4.x=z4.y=z4.z=z4.w=0; XA[(size_t)r * 256 + d4] = z4; }
}

// ---------------- weight transpose+convert: WcatT[1536][1024] bf16 ----------------
__global__ __launch_bounds__(256) void wconv(const float* __restrict__ Wz,
                                             const float* __restrict__ Wf,
                                             const float* __restrict__ Wo,
                                             ushort* __restrict__ WT) {
  __shared__ float tile[64][65];
  int z = blockIdx.z, g = z >> 1, i = z & 1;
  const float* src = (g == 0) ? Wz : (g == 1 ? Wf : Wo);
  src += (size_t)i * D * D;
  int d0 = blockIdx.x * 64, e0 = blockIdx.y * 64;
  int t = threadIdx.x, c = t & 63, rq = t >> 6;
#pragma unroll
  for (int p = 0; p < 16; ++p) {
    int dd = p * 4 + rq;
    tile[dd][c] = src[(size_t)(d0 + dd) * D + e0 + c];
  }
  __syncthreads();
#pragma unroll
  for (int p = 0; p < 16; ++p) {
    int ee = p * 4 + rq;
    WT[(size_t)(g * D + e0 + ee) * 1024 + i * D + d0 + c] = f2bf(tile[c][ee]);
  }
}

// ---------------- softmax weight transpose+convert: SWT[32000][512] bf16 ----------------
__global__ __launch_bounds__(256) void swconv(const float* __restrict__ SW,
                                              ushort* __restrict__ SWT) {
  __shared__ float tile[64][65];
  int k0 = blockIdx.x * 64, n0 = blockIdx.y * 64;
  int t = threadIdx.x, c = t & 63, rq = t >> 6;
#pragma unroll
  for (int p = 0; p < 16; ++p) {
    int kk = p * 4 + rq;
    tile[kk][c] = SW[(size_t)(k0 + kk) * V + n0 + c];
  }
  __syncthreads();
#pragma unroll
  for (int p = 0; p < 16; ++p) {
    int nn = p * 4 + rq;
    SWT[(size_t)(n0 + nn) * D + k0 + c] = f2bf(tile[c][nn]);
  }
}

// ---------------- bias concat ----------------
__global__ void bcat_kernel(const float* bz0, const float* bf0, const float* bo0,
                            const float* bz1, const float* bf1, const float* bo1,
                            float* BC0, float* BC1) {
  int idx = blockIdx.x * 256 + threadIdx.x;
  if (idx >= 2 * G3) return;
  int layer = idx / G3, rem = idx % G3, g = rem >> 9, e = rem & 511;
  const float* s = (layer == 0) ? (g == 0 ? bz0 : (g == 1 ? bf0 : bo0))
                                : (g == 0 ? bz1 : (g == 1 ? bf1 : bo1));
  (layer == 0 ? BC0 : BC1)[rem] = s[e];
}

// ---------------- round-2 single-buffer MFMA core (for gemm_pre) ----------------
// C[128x128] per 256-thread block (4 waves, 2x2 of 64x64 wave tiles, 4x4 frags).
// Known-good: 697 TF-class, ~2.5 blocks/CU cross-block overlap.
template<int KTOT, int LDA, int LDB>
__device__ __forceinline__ void gemm_tile_sb(const ushort* __restrict__ A,
                                             const ushort* __restrict__ B,
                                             int row0, int col0,
                                             char* As, char* Bs, f32x4 acc[4][4]) {
  const int t = threadIdx.x, lane = t & 63, w = t >> 6;
  const int wm = w >> 1, wn = w & 1;
  const int lrow = lane >> 3;
  const int slot = (lane & 7) ^ lrow;
  const int lo = lane & 15, hi = lane >> 4;

  const ushort* ga0 = A + (size_t)(row0 + w * 32 + lrow) * LDA + slot * 8;
  const ushort* gb0 = B + (size_t)(col0 + w * 32 + lrow) * LDB + slot * 8;

#pragma unroll 1
  for (int k0 = 0; k0 < KTOT; k0 += 64) {
#pragma unroll
    for (int i = 0; i < 4; ++i) {
      int chunk = w * 4 + i;
      gload16(ga0 + (size_t)i * 8 * LDA + k0, As + chunk * 1024);
      gload16(gb0 + (size_t)i * 8 * LDB + k0, Bs + chunk * 1024);
    }
    __syncthreads();
#pragma unroll
    for (int ks = 0; ks < 2; ++ks) {
      bf16x8 av[4], bv[4];
#pragma unroll
      for (int mi = 0; mi < 4; ++mi) {
        int row = wm * 64 + mi * 16 + lo;
        int sl  = (ks * 4 + hi) ^ (row & 7);
        av[mi] = *(const bf16x8*)(As + row * 128 + sl * 16);
      }
#pragma unroll
      for (int ni = 0; ni < 4; ++ni) {
        int row = wn * 64 + ni * 16 + lo;
        int sl  = (ks * 4 + hi) ^ (row & 7);
        bv[ni] = *(const bf16x8*)(Bs + row * 128 + sl * 16);
      }
#pragma unroll
      for (int mi = 0; mi < 4; ++mi)
#pragma unroll
        for (int ni = 0; ni < 4; ++ni)
          acc[mi][ni] = __builtin_amdgcn_mfma_f32_16x16x32_bf16(av[mi], bv[ni], acc[mi][ni], 0, 0, 0);
    }
    __syncthreads();
  }
}

// ---------------- QRNN pre-activation GEMM (8192x1536x1024) ----------------
__global__ __launch_bounds__(256) void gemm_pre(const ushort* __restrict__ A,
                                                const ushort* __restrict__ B,
                                                const float* __restrict__ bcat,
                                                ushort* __restrict__ PRE) {
  __shared__ char lds[32768];
  f32x4 acc[4][4];
#pragma unroll
  for (int i = 0; i < 4; ++i)
#pragma unroll
    for (int j = 0; j < 4; ++j) { f32x4 z = {0.f,0.f,0.f,0.f}; acc[i][j] = z; }
  const int row0 = blockIdx.x * 128, col0 = blockIdx.y * 128;
  gemm_tile_sb<1024,1024,1024>(A, B, row0, col0, lds, lds + 16384, acc);
  const int lane = threadIdx.x & 63, w = threadIdx.x >> 6;
  const int wm = w >> 1, wn = w & 1, lo = lane & 15, hi = lane >> 4;
#pragma unroll
  for (int ni = 0; ni < 4; ++ni) {
    int col = col0 + wn * 64 + ni * 16 + lo;
    float bb = bcat[col];
#pragma unroll
    for (int mi = 0; mi < 4; ++mi) {
      int r0 = row0 + wm * 64 + mi * 16 + hi * 4;
#pragma unroll
      for (int j = 0; j < 4; ++j)
        PRE[(size_t)(r0 + j) * G3 + col] = f2bf(acc[mi][ni][j] + bb);
    }
  }
}

// ---------------- 8-wave 256x256 phase-pipelined logits GEMM + fused LSE ----------------
// 512 threads = 8 waves (wm 0..1, wn 0..3); wave tile 128x64 (mi 0..7, ni 0..3).
// BK=64; LDS = 2 x (A 32KB + B 32KB) = 128KB dynamic. Raw s_barrier (no compiler
// vmcnt drain); vmcnt(0) ONCE per K-tile at tile top (next tile's 8 gload_lds
// issued 1-4 phases earlier -> latency hidden under MFMA); per-phase lgkmcnt(0)
// + sched_barrier (rule #18); setprio around each 16-MFMA cluster (T5).
// Race safety: stages into buf cur^1 only begin after the tile-top barrier,
// which every wave reaches only after its reads of cur^1 (prev tile) drained.
__global__ __launch_bounds__(512, 1) void gemm_lse8(const ushort* __restrict__ A,
                                                    const ushort* __restrict__ B,
                                                    const float* __restrict__ SB,
                                                    const int* __restrict__ tgt,
                                                    float* __restrict__ SUM,
                                                    float* __restrict__ TGL) {
  extern __shared__ char lds[];
  // bijective XCD swizzle over 4000 blocks (4000 % 8 == 0): runs of 32
  // consecutive in-XCD blocks share one B panel (256KB) -> L2 reuse.
  int wg  = blockIdx.x;
  int swz = (wg & 7) * 500 + (wg >> 3);
  int bx  = swz & 31;          // M block (32)
  int by  = swz >> 5;          // N block (125)
  const int row0 = bx * 256, col0 = by * 256;

  const int t = threadIdx.x, lane = t & 63, w = t >> 6;
  const int wm = w >> 2, wn = w & 3;
  const int lo = lane & 15, hi = lane >> 4;
  const int lrow = lane >> 3;
  const int slot = (lane & 7) ^ lrow;       // inverse-swizzled source 16B slot

  const ushort* ga0 = A + (size_t)(row0 + w * 32 + lrow) * 512 + slot * 8;
  const ushort* gb0 = B + (size_t)(col0 + w * 32 + lrow) * 512 + slot * 8;

  f32x4 acc[8][4];
#pragma unroll
  for (int i = 0; i < 8; ++i)
#pragma unroll
    for (int j = 0; j < 4; ++j) { f32x4 z = {0.f,0.f,0.f,0.f}; acc[i][j] = z; }

  // prologue: stage tile 0 into buf 0
#pragma unroll
  for (int i = 0; i < 4; ++i) {
    gload16(ga0 + (size_t)i * 8 * 512, lds + (w * 4 + i) * 1024);
    gload16(gb0 + (size_t)i * 8 * 512, lds + 32768 + (w * 4 + i) * 1024);
  }

#pragma unroll 1
  for (int kt = 0; kt < 8; ++kt) {
    const int cur = kt & 1;
    asm volatile("s_waitcnt vmcnt(0)" ::: "memory");   // tile kt landed (own calls)
    __builtin_amdgcn_sched_barrier(0);
    asm volatile("s_barrier" ::: "memory");            // all waves' stages landed
    const char* As = lds + cur * 65536;
    const char* Bs = As + 32768;
    char* As2 = lds + (cur ^ 1) * 65536;
    char* Bs2 = As2 + 32768;
    const size_t ko = (size_t)(kt + 1) * 64;

    bf16x8 bv[4][2];
#pragma unroll
    for (int q = 0; q < 4; ++q) {
      if (q == 0) {
#pragma unroll
        for (int ni = 0; ni < 4; ++ni)
#pragma unroll
          for (int ks = 0; ks < 2; ++ks) {
            int brow = wn * 64 + ni * 16 + lo;
            int sl   = (ks * 4 + hi) ^ (brow & 7);
            bv[ni][ks] = *(const bf16x8*)(Bs + brow * 128 + sl * 16);
          }
      }
      bf16x8 av[2][2];
#pragma unroll
      for (int mm = 0; mm < 2; ++mm)
#pragma unroll
        for (int ks = 0; ks < 2; ++ks) {
          int arow = wm * 128 + (q * 2 + mm) * 16 + lo;
          int sl   = (ks * 4 + hi) ^ (arow & 7);
          av[mm][ks] = *(const bf16x8*)(As + arow * 128 + sl * 16);
        }
      if (kt + 1 < 8) {   // stage one A-chunk + one B-chunk of tile kt+1
        gload16(ga0 + (size_t)q * 8 * 512 + ko, As2 + (w * 4 + q) * 1024);
        gload16(gb0 + (size_t)q * 8 * 512 + ko, Bs2 + (w * 4 + q) * 1024);
      }
      asm volatile("s_barrier" ::: "memory");
      asm volatile("s_waitcnt lgkmcnt(0)" ::: "memory");
      __builtin_amdgcn_sched_barrier(0);
      __builtin_amdgcn_s_setprio(1);
#pragma unroll
      for (int mm = 0; mm < 2; ++mm)
#pragma unroll
        for (int ni = 0; ni < 4; ++ni)
#pragma unroll
          for (int ks = 0; ks < 2; ++ks)
            acc[q * 2 + mm][ni] =
              __builtin_amdgcn_mfma_f32_16x16x32_bf16(av[mm][ks], bv[ni][ks],
                                                      acc[q * 2 + mm][ni], 0, 0, 0);
      __builtin_amdgcn_s_setprio(0);
      asm volatile("s_barrier" ::: "memory");
    }
  }

  // epilogue: bias, exp, per-row partial sums; capture target logit
#pragma unroll
  for (int mi = 0; mi < 8; ++mi) {
    int r0 = row0 + wm * 128 + mi * 16 + hi * 4;
    int tg[4];
    float s[4] = {0.f, 0.f, 0.f, 0.f};
#pragma unroll
    for (int j = 0; j < 4; ++j) tg[j] = tgt[r0 + j];
#pragma unroll
    for (int ni = 0; ni < 4; ++ni) {
      int col = col0 + wn * 64 + ni * 16 + lo;
      float bb = SB[col];
#pragma unroll
      for (int j = 0; j < 4; ++j) {
        float v = acc[mi][ni][j] + bb;
        if (col == tg[j]) TGL[r0 + j] = v;   // exactly one writer per row
        s[j] += __expf(v);
      }
    }
#pragma unroll
    for (int m = 1; m < 16; m <<= 1) {
#pragma unroll
      for (int j = 0; j < 4; ++j) s[j] += __shfl_xor(s[j], m, 64);
    }
    if (lo == 0) {
#pragma unroll
      for (int j = 0; j < 4; ++j) atomicAdd(&SUM[r0 + j], s[j]);
    }
  }
}

// ---------------- fo-pool scan (bf16 in, bf16 out in next-GEMM A layout) ----------------
__global__ __launch_bounds__(64) void scan_kernel(const ushort* __restrict__ PRE,
                                                  ushort* __restrict__ OUT, int mode) {
  int idx = blockIdx.x * 64 + threadIdx.x;    // 32*512
  int b = idx >> 9, d = idx & 511;
  const ushort* p = PRE + (size_t)b * TT * G3 + d;
  float c = 0.f;
  for (int t0 = 0; t0 < TT; t0 += 8) {
    float pz[8], pf[8], po[8];
#pragma unroll
    for (int i = 0; i < 8; ++i) {
      const ushort* q = p + (size_t)(t0 + i) * G3;
      pz[i] = bf2f(q[0]); pf[i] = bf2f(q[512]); po[i] = bf2f(q[1024]);
    }
#pragma unroll
    for (int i = 0; i < 8; ++i) {
      float z = 2.f / (1.f + __expf(-2.f * pz[i])) - 1.f;
      float f = 1.f / (1.f + __expf(-pf[i]));
      float o = 1.f / (1.f + __expf(-po[i]));
      c = f * c + (1.f - f) * z;
      float h = o * c;
      int tt = t0 + i;
      size_t r = (size_t)b * TT + tt;
      ushort hb = f2bf(h);
      if (mode == 0) {
        OUT[r * 1024 + 512 + d] = hb;
        if (tt < TT - 1) OUT[(r + 1) * 1024 + d] = hb;
        if (tt == 0)     OUT[r * 1024 + d] = 0;
      } else {
        OUT[r * 512 + d] = hb;
      }
    }
  }
}

// ---------------- helpers ----------------
__global__ void zero_kernel(float* __restrict__ p, int n) {
  int i = blockIdx.x * 256 + threadIdx.x;
  if (i < n) p[i] = 0.f;
}

__global__ __launch_bounds__(256) void cost_kernel(const float* __restrict__ sumexp,
                                                   const float* __restrict__ tgl,
                                                   float* __restrict__ out) {
  int t = threadIdx.x;
  float s = 0.f;
  for (int r = t; r < R; r += 256) s += logf(sumexp[r]) - tgl[r];
#pragma unroll
  for (int m = 1; m < 64; m <<= 1) s += __shfl_xor(s, m, 64);
  __shared__ float red[4];
  int wave = t >> 6, lane = t & 63;
  if (lane == 0) red[wave] = s;
  __syncthreads();
  if (t == 0) out[0] = (red[0] + red[1] + red[2] + red[3]) / (float)R;
}

extern "C" void kernel_launch(void* const* d_in, const int* in_sizes, int n_in,
                              void* d_out, int out_size, void* d_ws, size_t ws_size,
                              hipStream_t stream) {
  const int*   tok = (const int*)d_in[0];
  const int*   tgt = (const int*)d_in[1];
  const float* emb = (const float*)d_in[2];
  const float* Wz0 = (const float*)d_in[3];  const float* bz0 = (const float*)d_in[4];
  const float* Wf0 = (const float*)d_in[5];  const float* bf0 = (const float*)d_in[6];
  const float* Wo0 = (const float*)d_in[7];  const float* bo0 = (const float*)d_in[8];
  const float* Wz1 = (const float*)d_in[9];  const float* bz1 = (const float*)d_in[10];
  const float* Wf1 = (const float*)d_in[11]; const float* bf1 = (const float*)d_in[12];
  const float* Wo1 = (const float*)d_in[13]; const float* bo1 = (const float*)d_in[14];
  const float* SW  = (const float*)d_in[15]; const float* SB  = (const float*)d_in[16];
  float* out = (float*)d_out;

  // workspace layout (bytes), total ~70.1 MB:
  char* base = (char*)d_ws;
  ushort* XA  = (ushort*)(base);               // 16,777,216  [R][1024] bf16
  ushort* YA  = (ushort*)(base + 16777216);    // 16,777,216  [R][1024] bf16
  ushort* PRE = (ushort*)(base + 33554432);    // 25,165,824  [R][1536] bf16
  ushort* H2  = (ushort*)(base + 58720256);    //  8,388,608  [R][512]  bf16
  ushort* WT0 = (ushort*)(base + 67108864);    //  3,145,728  [1536][1024] bf16
  ushort* WT1 = (ushort*)(base + 70254592);    //  3,145,728
  float*  BC0 = (float*)(base + 73400320);     //  6,144
  float*  BC1 = (float*)(base + 73406464);     //  6,144
  float*  SUM = (float*)(base + 73412608);     //  32,768
  float*  TGL = (float*)(base + 73445376);     //  32,768
  ushort* SWT = (ushort*)(base);               // alias over XA+YA (32,768,000 <= 33,554,432)

  static bool attr_set = false;
  (void)attr_set;
  hipFuncSetAttribute((const void*)gemm_lse8,
                      hipFuncAttributeMaxDynamicSharedMemorySize, 131072);

  embed_kernel<<<R * 128 / 256, 256, 0, stream>>>(tok, (const float4*)emb, (ushort4*)XA);
  wconv<<<dim3(8, 8, 6), 256, 0, stream>>>(Wz0, Wf0, Wo0, WT0);
  wconv<<<dim3(8, 8, 6), 256, 0, stream>>>(Wz1, Wf1, Wo1, WT1);
  bcat_kernel<<<12, 256, 0, stream>>>(bz0, bf0, bo0, bz1, bf1, bo1, BC0, BC1);

  gemm_pre<<<dim3(64, 12), 256, 0, stream>>>(XA, WT0, BC0, PRE);
  scan_kernel<<<256, 64, 0, stream>>>(PRE, YA, 0);
  gemm_pre<<<dim3(64, 12), 256, 0, stream>>>(YA, WT1, BC1, PRE);
  scan_kernel<<<256, 64, 0, stream>>>(PRE, H2, 1);

  // SWT aliases XA/YA — both dead after the second gemm_pre
  swconv<<<dim3(8, 500), 256, 0, stream>>>(SW, SWT);
  zero_kernel<<<32, 256, 0, stream>>>(SUM, R);
  gemm_lse8<<<4000, 512, 131072, stream>>>(H2, SWT, SB, tgt, SUM, TGL);
  cost_kernel<<<1, 256, 0, stream>>>(SUM, TGL, out);
}

// Round 5
// 611.517 us; speedup vs baseline: 1.1340x; 1.1329x over previous
//
#include <hip/hip_runtime.h>
#include <hip/hip_bf16.h>
#include <math.h>

// Problem constants (B=32, T=256, V=32000, D=512)
#define R   8192    // B*T rows
#define TT  256
#define D   512
#define V   32000
#define G3  1536    // 3*D (z|f|o)

typedef __attribute__((ext_vector_type(8))) short bf16x8;
typedef __attribute__((ext_vector_type(4))) float f32x4;

__device__ __forceinline__ float bf2f(ushort u) {
  union { unsigned int i; float f; } x; x.i = ((unsigned int)u) << 16; return x.f;
}
__device__ __forceinline__ ushort f2bf(float f) {   // RNE
  union { float f; unsigned int i; } x; x.f = f;
  unsigned int r = x.i + 0x7fffu + ((x.i >> 16) & 1u);
  return (ushort)(r >> 16);
}

// f32 -> OCP e4m3fn, round-nearest-even, clamp to 448. Exact integer-grid method.
__device__ __forceinline__ unsigned char f2e4m3(float f) {
  unsigned char s = (__float_as_uint(f) >> 31) ? 0x80 : 0x00;
  float a = fabsf(f);
  if (!(a < 448.f)) return s | 0x7e;       // clamp (no NaN/overflow in our data)
  if (a == 0.f) return s;
  int ef; frexpf(a, &ef);                  // a = m*2^ef, m in [0.5,1)
  int E = ef - 1;                          // a = (2m)*2^E
  if (E < -6) E = -6;                      // denormal grid
  float ulp = ldexpf(1.f, E - 3);
  int qi = (int)rintf(a / ulp);            // exact scale (pow2), RNE, qi in [0,16]
  if (qi >= 16) { E += 1; qi = 8; }
  unsigned char bits = (qi < 8) ? (unsigned char)qi
                                : (unsigned char)(((E + 7) << 3) | (qi - 8));
  return s | bits;
}

__device__ __forceinline__ void gload16(const void* g, void* l) {
  __builtin_amdgcn_global_load_lds((const __attribute__((address_space(1))) void*)g,
                                   (__attribute__((address_space(3))) void*)l, 16, 0, 0);
}

// ---------------- embedding gather -> XA bf16 [R][1024] = [x_prev | x] ----------------
__global__ __launch_bounds__(256) void embed_kernel(const int* __restrict__ tok,
                                                    const float4* __restrict__ emb,
                                                    ushort4* __restrict__ XA) {
  int idx = blockIdx.x * 256 + threadIdx.x;   // over R*128 float4s
  int r = idx >> 7, d4 = idx & 127;
  float4 v = emb[(size_t)tok[r] * 128 + d4];
  ushort4 h; h.x = f2bf(v.x); h.y = f2bf(v.y); h.z = f2bf(v.z); h.w = f2bf(v.w);
  XA[(size_t)r * 256 + 128 + d4] = h;                       // x part
  int t = r & (TT - 1);
  if (t < TT - 1) XA[(size_t)(r + 1) * 256 + d4] = h;       // next row's x_prev
  if (t == 0) { ushort4 z4; z4.x=z4.y=z4.z=z4.w=0; XA[(size_t)r * 256 + d4] = z4; }
}

// ---------------- weight transpose+convert: WcatT[1536][1024] bf16 ----------------
__global__ __launch_bounds__(256) void wconv(const float* __restrict__ Wz,
                                             const float* __restrict__ Wf,
                                             const float* __restrict__ Wo,
                                             ushort* __restrict__ WT) {
  __shared__ float tile[64][65];
  int z = blockIdx.z, g = z >> 1, i = z & 1;
  const float* src = (g == 0) ? Wz : (g == 1 ? Wf : Wo);
  src += (size_t)i * D * D;
  int d0 = blockIdx.x * 64, e0 = blockIdx.y * 64;
  int t = threadIdx.x, c = t & 63, rq = t >> 6;
#pragma unroll
  for (int p = 0; p < 16; ++p) {
    int dd = p * 4 + rq;
    tile[dd][c] = src[(size_t)(d0 + dd) * D + e0 + c];
  }
  __syncthreads();
#pragma unroll
  for (int p = 0; p < 16; ++p) {
    int ee = p * 4 + rq;
    WT[(size_t)(g * D + e0 + ee) * 1024 + i * D + d0 + c] = f2bf(tile[c][ee]);
  }
}

// ---------------- softmax weight transpose+convert: SW8T[32000][512] fp8 ----------------
__global__ __launch_bounds__(256) void swconv(const float* __restrict__ SW,
                                              unsigned char* __restrict__ SWT) {
  __shared__ float tile[64][65];
  int k0 = blockIdx.x * 64, n0 = blockIdx.y * 64;
  int t = threadIdx.x, c = t & 63, rq = t >> 6;
#pragma unroll
  for (int p = 0; p < 16; ++p) {
    int kk = p * 4 + rq;
    tile[kk][c] = SW[(size_t)(k0 + kk) * V + n0 + c];
  }
  __syncthreads();
#pragma unroll
  for (int p = 0; p < 16; ++p) {
    int nn = p * 4 + rq;
    SWT[(size_t)(n0 + nn) * D + k0 + c] = f2e4m3(tile[c][nn]);
  }
}

// ---------------- bias concat ----------------
__global__ void bcat_kernel(const float* bz0, const float* bf0, const float* bo0,
                            const float* bz1, const float* bf1, const float* bo1,
                            float* BC0, float* BC1) {
  int idx = blockIdx.x * 256 + threadIdx.x;
  if (idx >= 2 * G3) return;
  int layer = idx / G3, rem = idx % G3, g = rem >> 9, e = rem & 511;
  const float* s = (layer == 0) ? (g == 0 ? bz0 : (g == 1 ? bf0 : bo0))
                                : (g == 0 ? bz1 : (g == 1 ? bf1 : bo1));
  (layer == 0 ? BC0 : BC1)[rem] = s[e];
}

// ---------------- round-2 single-buffer bf16 MFMA core (for gemm_pre) ----------------
// C[128x128] per 256-thread block (4 waves, 2x2 of 64x64 wave tiles, 4x4 frags).
template<int KTOT, int LDA, int LDB>
__device__ __forceinline__ void gemm_tile_sb(const ushort* __restrict__ A,
                                             const ushort* __restrict__ B,
                                             int row0, int col0,
                                             char* As, char* Bs, f32x4 acc[4][4]) {
  const int t = threadIdx.x, lane = t & 63, w = t >> 6;
  const int wm = w >> 1, wn = w & 1;
  const int lrow = lane >> 3;
  const int slot = (lane & 7) ^ lrow;
  const int lo = lane & 15, hi = lane >> 4;

  const ushort* ga0 = A + (size_t)(row0 + w * 32 + lrow) * LDA + slot * 8;
  const ushort* gb0 = B + (size_t)(col0 + w * 32 + lrow) * LDB + slot * 8;

#pragma unroll 1
  for (int k0 = 0; k0 < KTOT; k0 += 64) {
#pragma unroll
    for (int i = 0; i < 4; ++i) {
      int chunk = w * 4 + i;
      gload16(ga0 + (size_t)i * 8 * LDA + k0, As + chunk * 1024);
      gload16(gb0 + (size_t)i * 8 * LDB + k0, Bs + chunk * 1024);
    }
    __syncthreads();
#pragma unroll
    for (int ks = 0; ks < 2; ++ks) {
      bf16x8 av[4], bv[4];
#pragma unroll
      for (int mi = 0; mi < 4; ++mi) {
        int row = wm * 64 + mi * 16 + lo;
        int sl  = (ks * 4 + hi) ^ (row & 7);
        av[mi] = *(const bf16x8*)(As + row * 128 + sl * 16);
      }
#pragma unroll
      for (int ni = 0; ni < 4; ++ni) {
        int row = wn * 64 + ni * 16 + lo;
        int sl  = (ks * 4 + hi) ^ (row & 7);
        bv[ni] = *(const bf16x8*)(Bs + row * 128 + sl * 16);
      }
#pragma unroll
      for (int mi = 0; mi < 4; ++mi)
#pragma unroll
        for (int ni = 0; ni < 4; ++ni)
          acc[mi][ni] = __builtin_amdgcn_mfma_f32_16x16x32_bf16(av[mi], bv[ni], acc[mi][ni], 0, 0, 0);
    }
    __syncthreads();
  }
}

// ---------------- QRNN pre-activation GEMM (8192x1536x1024, bf16) ----------------
__global__ __launch_bounds__(256) void gemm_pre(const ushort* __restrict__ A,
                                                const ushort* __restrict__ B,
                                                const float* __restrict__ bcat,
                                                ushort* __restrict__ PRE) {
  __shared__ char lds[32768];
  f32x4 acc[4][4];
#pragma unroll
  for (int i = 0; i < 4; ++i)
#pragma unroll
    for (int j = 0; j < 4; ++j) { f32x4 z = {0.f,0.f,0.f,0.f}; acc[i][j] = z; }
  const int row0 = blockIdx.x * 128, col0 = blockIdx.y * 128;
  gemm_tile_sb<1024,1024,1024>(A, B, row0, col0, lds, lds + 16384, acc);
  const int lane = threadIdx.x & 63, w = threadIdx.x >> 6;
  const int wm = w >> 1, wn = w & 1, lo = lane & 15, hi = lane >> 4;
#pragma unroll
  for (int ni = 0; ni < 4; ++ni) {
    int col = col0 + wn * 64 + ni * 16 + lo;
    float bb = bcat[col];
#pragma unroll
    for (int mi = 0; mi < 4; ++mi) {
      int r0 = row0 + wm * 64 + mi * 16 + hi * 4;
#pragma unroll
      for (int j = 0; j < 4; ++j)
        PRE[(size_t)(r0 + j) * G3 + col] = f2bf(acc[mi][ni][j] + bb);
    }
  }
}

// ---------------- fp8 logits GEMM (8192x32000x512) + fused exp-sum + target ----------------
// Round-2 structure, fp8 operands: BK=128 (4 K-tiles), LDS 16KB A + 16KB B single-
// buffered. Per K-tile: 8 gload16/thread; frag reads are ds_read_b64 (8B = 8 fp8 =
// one K=32 slice). Logical 16B slot ls = ks*2 + (hi>>1); physical = ls ^ (row&7);
// within-slot byte = (hi&1)*8. Source pre-swizzled identically to bf16 core.
// LDS frag traffic halves vs bf16 (1KB/lane) -> block flips to MFMA-bound.
__global__ __launch_bounds__(256) void gemm_lse_fp8(const unsigned char* __restrict__ A,
                                                    const unsigned char* __restrict__ B,
                                                    const float* __restrict__ SB,
                                                    const int* __restrict__ tgt,
                                                    float* __restrict__ SUM,
                                                    float* __restrict__ TGL) {
  __shared__ char lds[32768];
  char* As = lds;
  char* Bs = lds + 16384;
  const int t = threadIdx.x, lane = t & 63, w = t >> 6;
  const int wm = w >> 1, wn = w & 1;
  const int lrow = lane >> 3;
  const int slot = (lane & 7) ^ lrow;        // inverse-swizzled source 16B slot
  const int lo = lane & 15, hi = lane >> 4;
  const int row0 = blockIdx.x * 128, col0 = blockIdx.y * 128;

  const unsigned char* ga0 = A + (size_t)(row0 + w * 32 + lrow) * 512 + slot * 16;
  const unsigned char* gb0 = B + (size_t)(col0 + w * 32 + lrow) * 512 + slot * 16;

  f32x4 acc[4][4];
#pragma unroll
  for (int i = 0; i < 4; ++i)
#pragma unroll
    for (int j = 0; j < 4; ++j) { f32x4 z = {0.f,0.f,0.f,0.f}; acc[i][j] = z; }

#pragma unroll 1
  for (int kt = 0; kt < 4; ++kt) {
    const int k0 = kt * 128;                 // byte == element offset (fp8)
#pragma unroll
    for (int i = 0; i < 4; ++i) {
      int chunk = w * 4 + i;
      gload16(ga0 + (size_t)i * 8 * 512 + k0, As + chunk * 1024);
      gload16(gb0 + (size_t)i * 8 * 512 + k0, Bs + chunk * 1024);
    }
    __syncthreads();
#pragma unroll
    for (int ks = 0; ks < 4; ++ks) {
      long av[4], bv[4];
#pragma unroll
      for (int mi = 0; mi < 4; ++mi) {
        int row = wm * 64 + mi * 16 + lo;
        int sl  = (ks * 2 + (hi >> 1)) ^ (row & 7);
        av[mi] = *(const long*)(As + row * 128 + sl * 16 + (hi & 1) * 8);
      }
#pragma unroll
      for (int ni = 0; ni < 4; ++ni) {
        int row = wn * 64 + ni * 16 + lo;
        int sl  = (ks * 2 + (hi >> 1)) ^ (row & 7);
        bv[ni] = *(const long*)(Bs + row * 128 + sl * 16 + (hi & 1) * 8);
      }
#pragma unroll
      for (int mi = 0; mi < 4; ++mi)
#pragma unroll
        for (int ni = 0; ni < 4; ++ni)
          acc[mi][ni] = __builtin_amdgcn_mfma_f32_16x16x32_fp8_fp8(av[mi], bv[ni], acc[mi][ni], 0, 0, 0);
    }
    __syncthreads();
  }

  // epilogue: bias, exp, per-row partial sums; capture target logit
#pragma unroll
  for (int mi = 0; mi < 4; ++mi) {
    int r0 = row0 + wm * 64 + mi * 16 + hi * 4;
    int tg[4];
    float s[4] = {0.f, 0.f, 0.f, 0.f};
#pragma unroll
    for (int j = 0; j < 4; ++j) tg[j] = tgt[r0 + j];
#pragma unroll
    for (int ni = 0; ni < 4; ++ni) {
      int col = col0 + wn * 64 + ni * 16 + lo;
      float bb = SB[col];
#pragma unroll
      for (int j = 0; j < 4; ++j) {
        float v = acc[mi][ni][j] + bb;
        if (col == tg[j]) TGL[r0 + j] = v;   // exactly one writer per row
        s[j] += __expf(v);
      }
    }
#pragma unroll
    for (int m = 1; m < 16; m <<= 1) {
#pragma unroll
      for (int j = 0; j < 4; ++j) s[j] += __shfl_xor(s[j], m, 64);
    }
    if (lo == 0) {
#pragma unroll
      for (int j = 0; j < 4; ++j) atomicAdd(&SUM[r0 + j], s[j]);
    }
  }
}

// ---------------- fo-pool scan (bf16 in; bf16 out mode 0, fp8 out mode 1) ----------------
__global__ __launch_bounds__(64) void scan_kernel(const ushort* __restrict__ PRE,
                                                  ushort* __restrict__ OUT16,
                                                  unsigned char* __restrict__ OUT8,
                                                  int mode) {
  int idx = blockIdx.x * 64 + threadIdx.x;    // 32*512
  int b = idx >> 9, d = idx & 511;
  const ushort* p = PRE + (size_t)b * TT * G3 + d;
  float c = 0.f;
  for (int t0 = 0; t0 < TT; t0 += 8) {
    float pz[8], pf[8], po[8];
#pragma unroll
    for (int i = 0; i < 8; ++i) {
      const ushort* q = p + (size_t)(t0 + i) * G3;
      pz[i] = bf2f(q[0]); pf[i] = bf2f(q[512]); po[i] = bf2f(q[1024]);
    }
#pragma unroll
    for (int i = 0; i < 8; ++i) {
      float z = 2.f / (1.f + __expf(-2.f * pz[i])) - 1.f;
      float f = 1.f / (1.f + __expf(-pf[i]));
      float o = 1.f / (1.f + __expf(-po[i]));
      c = f * c + (1.f - f) * z;
      float h = o * c;
      int tt = t0 + i;
      size_t r = (size_t)b * TT + tt;
      if (mode == 0) {
        ushort hb = f2bf(h);
        OUT16[r * 1024 + 512 + d] = hb;
        if (tt < TT - 1) OUT16[(r + 1) * 1024 + d] = hb;
        if (tt == 0)     OUT16[r * 1024 + d] = 0;
      } else {
        OUT8[r * 512 + d] = f2e4m3(h);
      }
    }
  }
}

// ---------------- helpers ----------------
__global__ void zero_kernel(float* __restrict__ p, int n) {
  int i = blockIdx.x * 256 + threadIdx.x;
  if (i < n) p[i] = 0.f;
}

__global__ __launch_bounds__(256) void cost_kernel(const float* __restrict__ sumexp,
                                                   const float* __restrict__ tgl,
                                                   float* __restrict__ out) {
  int t = threadIdx.x;
  float s = 0.f;
  for (int r = t; r < R; r += 256) s += logf(sumexp[r]) - tgl[r];
#pragma unroll
  for (int m = 1; m < 64; m <<= 1) s += __shfl_xor(s, m, 64);
  __shared__ float red[4];
  int wave = t >> 6, lane = t & 63;
  if (lane == 0) red[wave] = s;
  __syncthreads();
  if (t == 0) out[0] = (red[0] + red[1] + red[2] + red[3]) / (float)R;
}

extern "C" void kernel_launch(void* const* d_in, const int* in_sizes, int n_in,
                              void* d_out, int out_size, void* d_ws, size_t ws_size,
                              hipStream_t stream) {
  const int*   tok = (const int*)d_in[0];
  const int*   tgt = (const int*)d_in[1];
  const float* emb = (const float*)d_in[2];
  const float* Wz0 = (const float*)d_in[3];  const float* bz0 = (const float*)d_in[4];
  const float* Wf0 = (const float*)d_in[5];  const float* bf0 = (const float*)d_in[6];
  const float* Wo0 = (const float*)d_in[7];  const float* bo0 = (const float*)d_in[8];
  const float* Wz1 = (const float*)d_in[9];  const float* bz1 = (const float*)d_in[10];
  const float* Wf1 = (const float*)d_in[11]; const float* bf1 = (const float*)d_in[12];
  const float* Wo1 = (const float*)d_in[13]; const float* bo1 = (const float*)d_in[14];
  const float* SW  = (const float*)d_in[15]; const float* SB  = (const float*)d_in[16];
  float* out = (float*)d_out;

  // workspace layout (bytes):
  char* base = (char*)d_ws;
  ushort*        XA  = (ushort*)(base);               // 16,777,216  [R][1024] bf16
  ushort*        YA  = (ushort*)(base + 16777216);    // 16,777,216  [R][1024] bf16
  ushort*        PRE = (ushort*)(base + 33554432);    // 25,165,824  [R][1536] bf16
  unsigned char* H8  = (unsigned char*)(base + 58720256);  // 4,194,304 [R][512] fp8
  ushort*        WT0 = (ushort*)(base + 67108864);    //  3,145,728  [1536][1024] bf16
  ushort*        WT1 = (ushort*)(base + 70254592);    //  3,145,728
  float*         BC0 = (float*)(base + 73400320);     //  6,144
  float*         BC1 = (float*)(base + 73406464);     //  6,144
  float*         SUM = (float*)(base + 73412608);     //  32,768
  float*         TGL = (float*)(base + 73445376);     //  32,768
  unsigned char* SW8T = (unsigned char*)(base);       // 16,384,000 — aliases XA (dead by then)

  embed_kernel<<<R * 128 / 256, 256, 0, stream>>>(tok, (const float4*)emb, (ushort4*)XA);
  wconv<<<dim3(8, 8, 6), 256, 0, stream>>>(Wz0, Wf0, Wo0, WT0);
  wconv<<<dim3(8, 8, 6), 256, 0, stream>>>(Wz1, Wf1, Wo1, WT1);
  bcat_kernel<<<12, 256, 0, stream>>>(bz0, bf0, bo0, bz1, bf1, bo1, BC0, BC1);

  gemm_pre<<<dim3(64, 12), 256, 0, stream>>>(XA, WT0, BC0, PRE);
  scan_kernel<<<256, 64, 0, stream>>>(PRE, YA, nullptr, 0);
  gemm_pre<<<dim3(64, 12), 256, 0, stream>>>(YA, WT1, BC1, PRE);
  scan_kernel<<<256, 64, 0, stream>>>(PRE, nullptr, H8, 1);

  // SW8T aliases XA — dead after the first gemm_pre
  swconv<<<dim3(8, 500), 256, 0, stream>>>(SW, SW8T);
  zero_kernel<<<32, 256, 0, stream>>>(SUM, R);
  gemm_lse_fp8<<<dim3(64, 250), 256, 0, stream>>>(H8, SW8T, SB, tgt, SUM, TGL);
  cost_kernel<<<1, 256, 0, stream>>>(SUM, TGL, out);
}

// Round 6
// 582.255 us; speedup vs baseline: 1.1910x; 1.0503x over previous
//
#include <hip/hip_runtime.h>
#include <hip/hip_bf16.h>
#include <math.h>

// Problem constants (B=32, T=256, V=32000, D=512)
#define R   8192    // B*T rows
#define TT  256
#define D   512
#define V   32000
#define G3  1536    // 3*D (z|f|o)

typedef __attribute__((ext_vector_type(8))) short bf16x8;
typedef __attribute__((ext_vector_type(4))) float f32x4;
typedef __attribute__((ext_vector_type(4))) int   i32x4;

__device__ __forceinline__ float bf2f(ushort u) {
  union { unsigned int i; float f; } x; x.i = ((unsigned int)u) << 16; return x.f;
}
__device__ __forceinline__ ushort f2bf(float f) {   // RNE
  union { float f; unsigned int i; } x; x.f = f;
  unsigned int r = x.i + 0x7fffu + ((x.i >> 16) & 1u);
  return (ushort)(r >> 16);
}

// f32 -> OCP e4m3fn, round-nearest-even, clamp to 448. Exact integer-grid method.
__device__ __forceinline__ unsigned char f2e4m3(float f) {
  unsigned char s = (__float_as_uint(f) >> 31) ? 0x80 : 0x00;
  float a = fabsf(f);
  if (!(a < 448.f)) return s | 0x7e;       // clamp (no NaN/overflow in our data)
  if (a == 0.f) return s;
  int ef; frexpf(a, &ef);                  // a = m*2^ef, m in [0.5,1)
  int E = ef - 1;                          // a = (2m)*2^E
  if (E < -6) E = -6;                      // denormal grid
  float ulp = ldexpf(1.f, E - 3);
  int qi = (int)rintf(a / ulp);            // exact scale (pow2), RNE, qi in [0,16]
  if (qi >= 16) { E += 1; qi = 8; }
  unsigned char bits = (qi < 8) ? (unsigned char)qi
                                : (unsigned char)(((E + 7) << 3) | (qi - 8));
  return s | bits;
}

// phys-K transpose within each 128-elem block: element k stored at
// poff(k) = (k&~127) | h*32 | ks*8 | j  where k = (k&~127)+ks*32+h*8+j.
// Makes each MFMA lane's 4x8B K-slices contiguous 32B in LDS (b128 reads,
// conflict-free phases).
__device__ __forceinline__ int physk(int d) {
  return (d & ~127) | (((d >> 3) & 3) << 5) | (((d >> 5) & 3) << 3) | (d & 7);
}

__device__ __forceinline__ void gload16(const void* g, void* l) {
  __builtin_amdgcn_global_load_lds((const __attribute__((address_space(1))) void*)g,
                                   (__attribute__((address_space(3))) void*)l, 16, 0, 0);
}

// ---------------- embedding gather -> XA bf16 [R][1024] = [x_prev | x] ----------------
__global__ __launch_bounds__(256) void embed_kernel(const int* __restrict__ tok,
                                                    const float4* __restrict__ emb,
                                                    ushort4* __restrict__ XA) {
  int idx = blockIdx.x * 256 + threadIdx.x;   // over R*128 float4s
  int r = idx >> 7, d4 = idx & 127;
  float4 v = emb[(size_t)tok[r] * 128 + d4];
  ushort4 h; h.x = f2bf(v.x); h.y = f2bf(v.y); h.z = f2bf(v.z); h.w = f2bf(v.w);
  XA[(size_t)r * 256 + 128 + d4] = h;                       // x part
  int t = r & (TT - 1);
  if (t < TT - 1) XA[(size_t)(r + 1) * 256 + d4] = h;       // next row's x_prev
  if (t == 0) { ushort4 z4; z4.x=z4.y=z4.z=z4.w=0; XA[(size_t)r * 256 + d4] = z4; }
}

// ---------------- weight transpose+convert: WcatT[1536][1024] bf16 ----------------
__global__ __launch_bounds__(256) void wconv(const float* __restrict__ Wz,
                                             const float* __restrict__ Wf,
                                             const float* __restrict__ Wo,
                                             ushort* __restrict__ WT) {
  __shared__ float tile[64][65];
  int z = blockIdx.z, g = z >> 1, i = z & 1;
  const float* src = (g == 0) ? Wz : (g == 1 ? Wf : Wo);
  src += (size_t)i * D * D;
  int d0 = blockIdx.x * 64, e0 = blockIdx.y * 64;
  int t = threadIdx.x, c = t & 63, rq = t >> 6;
#pragma unroll
  for (int p = 0; p < 16; ++p) {
    int dd = p * 4 + rq;
    tile[dd][c] = src[(size_t)(d0 + dd) * D + e0 + c];
  }
  __syncthreads();
#pragma unroll
  for (int p = 0; p < 16; ++p) {
    int ee = p * 4 + rq;
    WT[(size_t)(g * D + e0 + ee) * 1024 + i * D + d0 + c] = f2bf(tile[c][ee]);
  }
}

// ---------------- softmax weight transpose+convert: SW8T[32000][512] fp8 phys-K ----------------
__global__ __launch_bounds__(256) void swconv(const float* __restrict__ SW,
                                              unsigned char* __restrict__ SWT) {
  __shared__ float tile[64][65];
  int k0 = blockIdx.x * 64, n0 = blockIdx.y * 64;
  int t = threadIdx.x, c = t & 63, rq = t >> 6;
#pragma unroll
  for (int p = 0; p < 16; ++p) {
    int kk = p * 4 + rq;
    tile[kk][c] = SW[(size_t)(k0 + kk) * V + n0 + c];
  }
  __syncthreads();
  int poff = physk(k0 + c);
#pragma unroll
  for (int p = 0; p < 16; ++p) {
    int nn = p * 4 + rq;
    SWT[(size_t)(n0 + nn) * D + poff] = f2e4m3(tile[c][nn]);
  }
}

// ---------------- bias concat ----------------
__global__ void bcat_kernel(const float* bz0, const float* bf0, const float* bo0,
                            const float* bz1, const float* bf1, const float* bo1,
                            float* BC0, float* BC1) {
  int idx = blockIdx.x * 256 + threadIdx.x;
  if (idx >= 2 * G3) return;
  int layer = idx / G3, rem = idx % G3, g = rem >> 9, e = rem & 511;
  const float* s = (layer == 0) ? (g == 0 ? bz0 : (g == 1 ? bf0 : bo0))
                                : (g == 0 ? bz1 : (g == 1 ? bf1 : bo1));
  (layer == 0 ? BC0 : BC1)[rem] = s[e];
}

// ---------------- round-2 single-buffer bf16 MFMA core (for gemm_pre) ----------------
// C[128x128] per 256-thread block (4 waves, 2x2 of 64x64 wave tiles, 4x4 frags).
template<int KTOT, int LDA, int LDB>
__device__ __forceinline__ void gemm_tile_sb(const ushort* __restrict__ A,
                                             const ushort* __restrict__ B,
                                             int row0, int col0,
                                             char* As, char* Bs, f32x4 acc[4][4]) {
  const int t = threadIdx.x, lane = t & 63, w = t >> 6;
  const int wm = w >> 1, wn = w & 1;
  const int lrow = lane >> 3;
  const int slot = (lane & 7) ^ lrow;
  const int lo = lane & 15, hi = lane >> 4;

  const ushort* ga0 = A + (size_t)(row0 + w * 32 + lrow) * LDA + slot * 8;
  const ushort* gb0 = B + (size_t)(col0 + w * 32 + lrow) * LDB + slot * 8;

#pragma unroll 1
  for (int k0 = 0; k0 < KTOT; k0 += 64) {
#pragma unroll
    for (int i = 0; i < 4; ++i) {
      int chunk = w * 4 + i;
      gload16(ga0 + (size_t)i * 8 * LDA + k0, As + chunk * 1024);
      gload16(gb0 + (size_t)i * 8 * LDB + k0, Bs + chunk * 1024);
    }
    __syncthreads();
#pragma unroll
    for (int ks = 0; ks < 2; ++ks) {
      bf16x8 av[4], bv[4];
#pragma unroll
      for (int mi = 0; mi < 4; ++mi) {
        int row = wm * 64 + mi * 16 + lo;
        int sl  = (ks * 4 + hi) ^ (row & 7);
        av[mi] = *(const bf16x8*)(As + row * 128 + sl * 16);
      }
#pragma unroll
      for (int ni = 0; ni < 4; ++ni) {
        int row = wn * 64 + ni * 16 + lo;
        int sl  = (ks * 4 + hi) ^ (row & 7);
        bv[ni] = *(const bf16x8*)(Bs + row * 128 + sl * 16);
      }
#pragma unroll
      for (int mi = 0; mi < 4; ++mi)
#pragma unroll
        for (int ni = 0; ni < 4; ++ni)
          acc[mi][ni] = __builtin_amdgcn_mfma_f32_16x16x32_bf16(av[mi], bv[ni], acc[mi][ni], 0, 0, 0);
    }
    __syncthreads();
  }
}

// ---------------- QRNN pre-activation GEMM (8192x1536x1024, bf16) ----------------
__global__ __launch_bounds__(256) void gemm_pre(const ushort* __restrict__ A,
                                                const ushort* __restrict__ B,
                                                const float* __restrict__ bcat,
                                                ushort* __restrict__ PRE) {
  __shared__ char lds[32768];
  f32x4 acc[4][4];
#pragma unroll
  for (int i = 0; i < 4; ++i)
#pragma unroll
    for (int j = 0; j < 4; ++j) { f32x4 z = {0.f,0.f,0.f,0.f}; acc[i][j] = z; }
  const int row0 = blockIdx.x * 128, col0 = blockIdx.y * 128;
  gemm_tile_sb<1024,1024,1024>(A, B, row0, col0, lds, lds + 16384, acc);
  const int lane = threadIdx.x & 63, w = threadIdx.x >> 6;
  const int wm = w >> 1, wn = w & 1, lo = lane & 15, hi = lane >> 4;
#pragma unroll
  for (int ni = 0; ni < 4; ++ni) {
    int col = col0 + wn * 64 + ni * 16 + lo;
    float bb = bcat[col];
#pragma unroll
    for (int mi = 0; mi < 4; ++mi) {
      int r0 = row0 + wm * 64 + mi * 16 + hi * 4;
#pragma unroll
      for (int j = 0; j < 4; ++j)
        PRE[(size_t)(r0 + j) * G3 + col] = f2bf(acc[mi][ni][j] + bb);
    }
  }
}

// ---------------- fp8 logits GEMM (8192x32000x512) + fused exp-sum + target ----------------
// v2: phys-K operand layout. BK=256 (2 K-tiles), LDS = A 32KB + B 32KB single-
// buffered (64KB -> 2 blocks/CU for cross-block drain hiding). Rows are 256B =
// 16 slots of 16B; slot s of row r stored at LDS slot (s&8)|((s&7)^(r&7)) via
// pre-swizzled per-lane global source (rule #21). Fragment loads: per (mi,kb)
// two ds_read_b128 at logical slots kb*8+hi*2{,+1} -> lane's 4 K-slices (8B
// each) land contiguously; 16-lane phases span all 32 banks (conflict-free).
__global__ __launch_bounds__(256, 2) void gemm_lse_fp8(const unsigned char* __restrict__ A,
                                                       const unsigned char* __restrict__ B,
                                                       const float* __restrict__ SB,
                                                       const int* __restrict__ tgt,
                                                       float* __restrict__ SUM,
                                                       float* __restrict__ TGL) {
  __shared__ char lds[65536];
  char* As = lds;
  char* Bs = lds + 32768;
  const int t = threadIdx.x, lane = t & 63, w = t >> 6;
  const int wm = w >> 1, wn = w & 1;
  const int lo = lane & 15, hi = lane >> 4;
  const int row0 = blockIdx.x * 128, col0 = blockIdx.y * 128;

  f32x4 acc[4][4];
#pragma unroll
  for (int i = 0; i < 4; ++i)
#pragma unroll
    for (int j = 0; j < 4; ++j) { f32x4 z = {0.f,0.f,0.f,0.f}; acc[i][j] = z; }

  // per-lane staging geometry: issue i covers 4 rows (lane>>4), slot = lane&15
  const int srow = lane >> 4;        // row within 4-row issue
  const int sd   = lane & 15;        // dest slot

#pragma unroll 1
  for (int kt = 0; kt < 2; ++kt) {
    // ---- stage A[128x256] + B[128x256] (phys-K layout in global) ----
#pragma unroll
    for (int i = 0; i < 8; ++i) {
      int rr = w * 32 + i * 4 + srow;
      int ss = (sd & 8) | ((sd & 7) ^ (rr & 7));   // inverse-swizzled source slot
      gload16(A + (size_t)(row0 + rr) * 512 + kt * 256 + ss * 16,
              As + (size_t)(w * 32 + i * 4) * 256);
      gload16(B + (size_t)(col0 + rr) * 512 + kt * 256 + ss * 16,
              Bs + (size_t)(w * 32 + i * 4) * 256);
    }
    __syncthreads();
    // ---- compute: 2 x 128-K blocks, 4 x K=32 slices each ----
#pragma unroll
    for (int kb = 0; kb < 2; ++kb) {
      long a_ks[4][4], b_ks[4][4];
#pragma unroll
      for (int mi = 0; mi < 4; ++mi) {
        int ar = wm * 64 + mi * 16 + lo;
        const char* rb = As + ar * 256 + kb * 128;
        int x = ar & 7;
        union { i32x4 v; long l[2]; } u0, u1;
        u0.v = *(const i32x4*)(rb + ((hi * 2 + 0) ^ x) * 16);
        u1.v = *(const i32x4*)(rb + ((hi * 2 + 1) ^ x) * 16);
        a_ks[mi][0] = u0.l[0]; a_ks[mi][1] = u0.l[1];
        a_ks[mi][2] = u1.l[0]; a_ks[mi][3] = u1.l[1];
      }
#pragma unroll
      for (int ni = 0; ni < 4; ++ni) {
        int br = wn * 64 + ni * 16 + lo;
        const char* rb = Bs + br * 256 + kb * 128;
        int x = br & 7;
        union { i32x4 v; long l[2]; } u0, u1;
        u0.v = *(const i32x4*)(rb + ((hi * 2 + 0) ^ x) * 16);
        u1.v = *(const i32x4*)(rb + ((hi * 2 + 1) ^ x) * 16);
        b_ks[ni][0] = u0.l[0]; b_ks[ni][1] = u0.l[1];
        b_ks[ni][2] = u1.l[0]; b_ks[ni][3] = u1.l[1];
      }
#pragma unroll
      for (int q = 0; q < 4; ++q)
#pragma unroll
        for (int mi = 0; mi < 4; ++mi)
#pragma unroll
          for (int ni = 0; ni < 4; ++ni)
            acc[mi][ni] = __builtin_amdgcn_mfma_f32_16x16x32_fp8_fp8(
                a_ks[mi][q], b_ks[ni][q], acc[mi][ni], 0, 0, 0);
    }
    __syncthreads();
  }

  // epilogue: bias, exp, per-row partial sums; capture target logit
#pragma unroll
  for (int mi = 0; mi < 4; ++mi) {
    int r0 = row0 + wm * 64 + mi * 16 + hi * 4;
    int tg[4];
    float s[4] = {0.f, 0.f, 0.f, 0.f};
#pragma unroll
    for (int j = 0; j < 4; ++j) tg[j] = tgt[r0 + j];
#pragma unroll
    for (int ni = 0; ni < 4; ++ni) {
      int col = col0 + wn * 64 + ni * 16 + lo;
      float bb = SB[col];
#pragma unroll
      for (int j = 0; j < 4; ++j) {
        float v = acc[mi][ni][j] + bb;
        if (col == tg[j]) TGL[r0 + j] = v;   // exactly one writer per row
        s[j] += __expf(v);
      }
    }
#pragma unroll
    for (int m = 1; m < 16; m <<= 1) {
#pragma unroll
      for (int j = 0; j < 4; ++j) s[j] += __shfl_xor(s[j], m, 64);
    }
    if (lo == 0) {
#pragma unroll
      for (int j = 0; j < 4; ++j) atomicAdd(&SUM[r0 + j], s[j]);
    }
  }
}

// ---------------- fo-pool scan (bf16 in; bf16 out mode 0, phys-K fp8 out mode 1) ----------------
__global__ __launch_bounds__(64) void scan_kernel(const ushort* __restrict__ PRE,
                                                  ushort* __restrict__ OUT16,
                                                  unsigned char* __restrict__ OUT8,
                                                  int mode) {
  int idx = blockIdx.x * 64 + threadIdx.x;    // 32*512
  int b = idx >> 9, d = idx & 511;
  const ushort* p = PRE + (size_t)b * TT * G3 + d;
  int poff = physk(d);
  float c = 0.f;
  for (int t0 = 0; t0 < TT; t0 += 8) {
    float pz[8], pf[8], po[8];
#pragma unroll
    for (int i = 0; i < 8; ++i) {
      const ushort* q = p + (size_t)(t0 + i) * G3;
      pz[i] = bf2f(q[0]); pf[i] = bf2f(q[512]); po[i] = bf2f(q[1024]);
    }
#pragma unroll
    for (int i = 0; i < 8; ++i) {
      float z = 2.f / (1.f + __expf(-2.f * pz[i])) - 1.f;
      float f = 1.f / (1.f + __expf(-pf[i]));
      float o = 1.f / (1.f + __expf(-po[i]));
      c = f * c + (1.f - f) * z;
      float h = o * c;
      int tt = t0 + i;
      size_t r = (size_t)b * TT + tt;
      if (mode == 0) {
        ushort hb = f2bf(h);
        OUT16[r * 1024 + 512 + d] = hb;
        if (tt < TT - 1) OUT16[(r + 1) * 1024 + d] = hb;
        if (tt == 0)     OUT16[r * 1024 + d] = 0;
      } else {
        OUT8[r * 512 + poff] = f2e4m3(h);
      }
    }
  }
}

// ---------------- helpers ----------------
__global__ void zero_kernel(float* __restrict__ p, int n) {
  int i = blockIdx.x * 256 + threadIdx.x;
  if (i < n) p[i] = 0.f;
}

__global__ __launch_bounds__(256) void cost_kernel(const float* __restrict__ sumexp,
                                                   const float* __restrict__ tgl,
                                                   float* __restrict__ out) {
  int t = threadIdx.x;
  float s = 0.f;
  for (int r = t; r < R; r += 256) s += logf(sumexp[r]) - tgl[r];
#pragma unroll
  for (int m = 1; m < 64; m <<= 1) s += __shfl_xor(s, m, 64);
  __shared__ float red[4];
  int wave = t >> 6, lane = t & 63;
  if (lane == 0) red[wave] = s;
  __syncthreads();
  if (t == 0) out[0] = (red[0] + red[1] + red[2] + red[3]) / (float)R;
}

extern "C" void kernel_launch(void* const* d_in, const int* in_sizes, int n_in,
                              void* d_out, int out_size, void* d_ws, size_t ws_size,
                              hipStream_t stream) {
  const int*   tok = (const int*)d_in[0];
  const int*   tgt = (const int*)d_in[1];
  const float* emb = (const float*)d_in[2];
  const float* Wz0 = (const float*)d_in[3];  const float* bz0 = (const float*)d_in[4];
  const float* Wf0 = (const float*)d_in[5];  const float* bf0 = (const float*)d_in[6];
  const float* Wo0 = (const float*)d_in[7];  const float* bo0 = (const float*)d_in[8];
  const float* Wz1 = (const float*)d_in[9];  const float* bz1 = (const float*)d_in[10];
  const float* Wf1 = (const float*)d_in[11]; const float* bf1 = (const float*)d_in[12];
  const float* Wo1 = (const float*)d_in[13]; const float* bo1 = (const float*)d_in[14];
  const float* SW  = (const float*)d_in[15]; const float* SB  = (const float*)d_in[16];
  float* out = (float*)d_out;

  // workspace layout (bytes):
  char* base = (char*)d_ws;
  ushort*        XA  = (ushort*)(base);               // 16,777,216  [R][1024] bf16
  ushort*        YA  = (ushort*)(base + 16777216);    // 16,777,216  [R][1024] bf16
  ushort*        PRE = (ushort*)(base + 33554432);    // 25,165,824  [R][1536] bf16
  unsigned char* H8  = (unsigned char*)(base + 58720256);  // 4,194,304 [R][512] fp8 phys-K
  ushort*        WT0 = (ushort*)(base + 67108864);    //  3,145,728  [1536][1024] bf16
  ushort*        WT1 = (ushort*)(base + 70254592);    //  3,145,728
  float*         BC0 = (float*)(base + 73400320);     //  6,144
  float*         BC1 = (float*)(base + 73406464);     //  6,144
  float*         SUM = (float*)(base + 73412608);     //  32,768
  float*         TGL = (float*)(base + 73445376);     //  32,768
  unsigned char* SW8T = (unsigned char*)(base);       // 16,384,000 — aliases XA (dead by then)

  embed_kernel<<<R * 128 / 256, 256, 0, stream>>>(tok, (const float4*)emb, (ushort4*)XA);
  wconv<<<dim3(8, 8, 6), 256, 0, stream>>>(Wz0, Wf0, Wo0, WT0);
  wconv<<<dim3(8, 8, 6), 256, 0, stream>>>(Wz1, Wf1, Wo1, WT1);
  bcat_kernel<<<12, 256, 0, stream>>>(bz0, bf0, bo0, bz1, bf1, bo1, BC0, BC1);

  gemm_pre<<<dim3(64, 12), 256, 0, stream>>>(XA, WT0, BC0, PRE);
  scan_kernel<<<256, 64, 0, stream>>>(PRE, YA, nullptr, 0);
  gemm_pre<<<dim3(64, 12), 256, 0, stream>>>(YA, WT1, BC1, PRE);
  scan_kernel<<<256, 64, 0, stream>>>(PRE, nullptr, H8, 1);

  // SW8T aliases XA — dead after the first gemm_pre
  swconv<<<dim3(8, 500), 256, 0, stream>>>(SW, SW8T);
  zero_kernel<<<32, 256, 0, stream>>>(SUM, R);
  gemm_lse_fp8<<<dim3(64, 250), 256, 0, stream>>>(H8, SW8T, SB, tgt, SUM, TGL);
  cost_kernel<<<1, 256, 0, stream>>>(SUM, TGL, out);
}

// Round 7
// 549.777 us; speedup vs baseline: 1.2613x; 1.0591x over previous
//
#include <hip/hip_runtime.h>
#include <hip/hip_bf16.h>
#include <math.h>

// Problem constants (B=32, T=256, V=32000, D=512)
#define R   8192    // B*T rows
#define TT  256
#define D   512
#define V   32000
#define G3  1536    // 3*D (z|f|o)

typedef __attribute__((ext_vector_type(8))) short bf16x8;
typedef __attribute__((ext_vector_type(4))) float f32x4;
typedef __attribute__((ext_vector_type(4))) int   i32x4;
typedef __attribute__((ext_vector_type(8))) int   i32x8;

__device__ __forceinline__ float bf2f(ushort u) {
  union { unsigned int i; float f; } x; x.i = ((unsigned int)u) << 16; return x.f;
}
__device__ __forceinline__ ushort f2bf(float f) {   // RNE
  union { float f; unsigned int i; } x; x.f = f;
  unsigned int r = x.i + 0x7fffu + ((x.i >> 16) & 1u);
  return (ushort)(r >> 16);
}

// f32 -> OCP e4m3fn, round-nearest-even, clamp to 448. Exact integer-grid method.
__device__ __forceinline__ unsigned char f2e4m3(float f) {
  unsigned char s = (__float_as_uint(f) >> 31) ? 0x80 : 0x00;
  float a = fabsf(f);
  if (!(a < 448.f)) return s | 0x7e;       // clamp (no NaN/overflow in our data)
  if (a == 0.f) return s;
  int ef; frexpf(a, &ef);                  // a = m*2^ef, m in [0.5,1)
  int E = ef - 1;                          // a = (2m)*2^E
  if (E < -6) E = -6;                      // denormal grid
  float ulp = ldexpf(1.f, E - 3);
  int qi = (int)rintf(a / ulp);            // exact scale (pow2), RNE, qi in [0,16]
  if (qi >= 16) { E += 1; qi = 8; }
  unsigned char bits = (qi < 8) ? (unsigned char)qi
                                : (unsigned char)(((E + 7) << 3) | (qi - 8));
  return s | bits;
}

// phys-K transpose within each 128-elem block: element k stored at
// poff(k) = (k&~127) | h*32 | ks*8 | j  where k = (k&~127)+ks*32+h*8+j.
// Lane h's 4x8B K-slices (ks=0..3) land contiguous 32B -> the exact v8i32
// operand of the K=128 scaled MFMA.
__device__ __forceinline__ int physk(int d) {
  return (d & ~127) | (((d >> 3) & 3) << 5) | (((d >> 5) & 3) << 3) | (d & 7);
}

__device__ __forceinline__ void gload16(const void* g, void* l) {
  __builtin_amdgcn_global_load_lds((const __attribute__((address_space(1))) void*)g,
                                   (__attribute__((address_space(3))) void*)l, 16, 0, 0);
}

// ---------------- embedding gather -> XA bf16 [R][1024] = [x_prev | x] ----------------
__global__ __launch_bounds__(256) void embed_kernel(const int* __restrict__ tok,
                                                    const float4* __restrict__ emb,
                                                    ushort4* __restrict__ XA) {
  int idx = blockIdx.x * 256 + threadIdx.x;   // over R*128 float4s
  int r = idx >> 7, d4 = idx & 127;
  float4 v = emb[(size_t)tok[r] * 128 + d4];
  ushort4 h; h.x = f2bf(v.x); h.y = f2bf(v.y); h.z = f2bf(v.z); h.w = f2bf(v.w);
  XA[(size_t)r * 256 + 128 + d4] = h;                       // x part
  int t = r & (TT - 1);
  if (t < TT - 1) XA[(size_t)(r + 1) * 256 + d4] = h;       // next row's x_prev
  if (t == 0) { ushort4 z4; z4.x=z4.y=z4.z=z4.w=0; XA[(size_t)r * 256 + d4] = z4; }
}

// ---------------- weight transpose+convert: WcatT[1536][1024] bf16 ----------------
__global__ __launch_bounds__(256) void wconv(const float* __restrict__ Wz,
                                             const float* __restrict__ Wf,
                                             const float* __restrict__ Wo,
                                             ushort* __restrict__ WT) {
  __shared__ float tile[64][65];
  int z = blockIdx.z, g = z >> 1, i = z & 1;
  const float* src = (g == 0) ? Wz : (g == 1 ? Wf : Wo);
  src += (size_t)i * D * D;
  int d0 = blockIdx.x * 64, e0 = blockIdx.y * 64;
  int t = threadIdx.x, c = t & 63, rq = t >> 6;
#pragma unroll
  for (int p = 0; p < 16; ++p) {
    int dd = p * 4 + rq;
    tile[dd][c] = src[(size_t)(d0 + dd) * D + e0 + c];
  }
  __syncthreads();
#pragma unroll
  for (int p = 0; p < 16; ++p) {
    int ee = p * 4 + rq;
    WT[(size_t)(g * D + e0 + ee) * 1024 + i * D + d0 + c] = f2bf(tile[c][ee]);
  }
}

// ---------------- softmax weight transpose+convert: SW8T[32000][512] fp8 phys-K ----------------
__global__ __launch_bounds__(256) void swconv(const float* __restrict__ SW,
                                              unsigned char* __restrict__ SWT) {
  __shared__ float tile[64][65];
  int k0 = blockIdx.x * 64, n0 = blockIdx.y * 64;
  int t = threadIdx.x, c = t & 63, rq = t >> 6;
#pragma unroll
  for (int p = 0; p < 16; ++p) {
    int kk = p * 4 + rq;
    tile[kk][c] = SW[(size_t)(k0 + kk) * V + n0 + c];
  }
  __syncthreads();
  int poff = physk(k0 + c);
#pragma unroll
  for (int p = 0; p < 16; ++p) {
    int nn = p * 4 + rq;
    SWT[(size_t)(n0 + nn) * D + poff] = f2e4m3(tile[c][nn]);
  }
}

// ---------------- bias concat ----------------
__global__ void bcat_kernel(const float* bz0, const float* bf0, const float* bo0,
                            const float* bz1, const float* bf1, const float* bo1,
                            float* BC0, float* BC1) {
  int idx = blockIdx.x * 256 + threadIdx.x;
  if (idx >= 2 * G3) return;
  int layer = idx / G3, rem = idx % G3, g = rem >> 9, e = rem & 511;
  const float* s = (layer == 0) ? (g == 0 ? bz0 : (g == 1 ? bf0 : bo0))
                                : (g == 0 ? bz1 : (g == 1 ? bf1 : bo1));
  (layer == 0 ? BC0 : BC1)[rem] = s[e];
}

// ---------------- round-2 single-buffer bf16 MFMA core (for gemm_pre) ----------------
// C[128x128] per 256-thread block (4 waves, 2x2 of 64x64 wave tiles, 4x4 frags).
template<int KTOT, int LDA, int LDB>
__device__ __forceinline__ void gemm_tile_sb(const ushort* __restrict__ A,
                                             const ushort* __restrict__ B,
                                             int row0, int col0,
                                             char* As, char* Bs, f32x4 acc[4][4]) {
  const int t = threadIdx.x, lane = t & 63, w = t >> 6;
  const int wm = w >> 1, wn = w & 1;
  const int lrow = lane >> 3;
  const int slot = (lane & 7) ^ lrow;
  const int lo = lane & 15, hi = lane >> 4;

  const ushort* ga0 = A + (size_t)(row0 + w * 32 + lrow) * LDA + slot * 8;
  const ushort* gb0 = B + (size_t)(col0 + w * 32 + lrow) * LDB + slot * 8;

#pragma unroll 1
  for (int k0 = 0; k0 < KTOT; k0 += 64) {
#pragma unroll
    for (int i = 0; i < 4; ++i) {
      int chunk = w * 4 + i;
      gload16(ga0 + (size_t)i * 8 * LDA + k0, As + chunk * 1024);
      gload16(gb0 + (size_t)i * 8 * LDB + k0, Bs + chunk * 1024);
    }
    __syncthreads();
#pragma unroll
    for (int ks = 0; ks < 2; ++ks) {
      bf16x8 av[4], bv[4];
#pragma unroll
      for (int mi = 0; mi < 4; ++mi) {
        int row = wm * 64 + mi * 16 + lo;
        int sl  = (ks * 4 + hi) ^ (row & 7);
        av[mi] = *(const bf16x8*)(As + row * 128 + sl * 16);
      }
#pragma unroll
      for (int ni = 0; ni < 4; ++ni) {
        int row = wn * 64 + ni * 16 + lo;
        int sl  = (ks * 4 + hi) ^ (row & 7);
        bv[ni] = *(const bf16x8*)(Bs + row * 128 + sl * 16);
      }
#pragma unroll
      for (int mi = 0; mi < 4; ++mi)
#pragma unroll
        for (int ni = 0; ni < 4; ++ni)
          acc[mi][ni] = __builtin_amdgcn_mfma_f32_16x16x32_bf16(av[mi], bv[ni], acc[mi][ni], 0, 0, 0);
    }
    __syncthreads();
  }
}

// ---------------- QRNN pre-activation GEMM (8192x1536x1024, bf16) ----------------
__global__ __launch_bounds__(256) void gemm_pre(const ushort* __restrict__ A,
                                                const ushort* __restrict__ B,
                                                const float* __restrict__ bcat,
                                                ushort* __restrict__ PRE) {
  __shared__ char lds[32768];
  f32x4 acc[4][4];
#pragma unroll
  for (int i = 0; i < 4; ++i)
#pragma unroll
    for (int j = 0; j < 4; ++j) { f32x4 z = {0.f,0.f,0.f,0.f}; acc[i][j] = z; }
  const int row0 = blockIdx.x * 128, col0 = blockIdx.y * 128;
  gemm_tile_sb<1024,1024,1024>(A, B, row0, col0, lds, lds + 16384, acc);
  const int lane = threadIdx.x & 63, w = threadIdx.x >> 6;
  const int wm = w >> 1, wn = w & 1, lo = lane & 15, hi = lane >> 4;
#pragma unroll
  for (int ni = 0; ni < 4; ++ni) {
    int col = col0 + wn * 64 + ni * 16 + lo;
    float bb = bcat[col];
#pragma unroll
    for (int mi = 0; mi < 4; ++mi) {
      int r0 = row0 + wm * 64 + mi * 16 + hi * 4;
#pragma unroll
      for (int j = 0; j < 4; ++j)
        PRE[(size_t)(r0 + j) * G3 + col] = f2bf(acc[mi][ni][j] + bb);
    }
  }
}

// ---------------- MX-fp8 logits GEMM (8192x32000x512) + fused exp-sum + target ----------------
// v3: phys-K layout + K=128 scaled MFMA (scales=1.0). BK=256 (2 K-tiles),
// LDS = A 32KB + B 32KB single-buffered (2 blocks/CU). Per (mi,kb): two
// ds_read_b128 deliver the lane's contiguous 32B = v8i32 operand; one
// mfma_scale_f32_16x16x128_f8f6f4 replaces four 16x16x32 fp8 MFMAs.
// k-permutation inside the instruction cancels (A,B share the lane->k map).
__global__ __launch_bounds__(256, 2) void gemm_lse_fp8(const unsigned char* __restrict__ A,
                                                       const unsigned char* __restrict__ B,
                                                       const float* __restrict__ SB,
                                                       const int* __restrict__ tgt,
                                                       float* __restrict__ SUM,
                                                       float* __restrict__ TGL) {
  __shared__ char lds[65536];
  char* As = lds;
  char* Bs = lds + 32768;
  const int t = threadIdx.x, lane = t & 63, w = t >> 6;
  const int wm = w >> 1, wn = w & 1;
  const int lo = lane & 15, hi = lane >> 4;
  const int row0 = blockIdx.x * 128, col0 = blockIdx.y * 128;

  f32x4 acc[4][4];
#pragma unroll
  for (int i = 0; i < 4; ++i)
#pragma unroll
    for (int j = 0; j < 4; ++j) { f32x4 z = {0.f,0.f,0.f,0.f}; acc[i][j] = z; }

  // per-lane staging geometry: issue i covers 4 rows (lane>>4), slot = lane&15
  const int srow = lane >> 4;        // row within 4-row issue
  const int sd   = lane & 15;        // dest slot

#pragma unroll 1
  for (int kt = 0; kt < 2; ++kt) {
    // ---- stage A[128x256] + B[128x256] (phys-K layout in global) ----
#pragma unroll
    for (int i = 0; i < 8; ++i) {
      int rr = w * 32 + i * 4 + srow;
      int ss = (sd & 8) | ((sd & 7) ^ (rr & 7));   // inverse-swizzled source slot
      gload16(A + (size_t)(row0 + rr) * 512 + kt * 256 + ss * 16,
              As + (size_t)(w * 32 + i * 4) * 256);
      gload16(B + (size_t)(col0 + rr) * 512 + kt * 256 + ss * 16,
              Bs + (size_t)(w * 32 + i * 4) * 256);
    }
    __syncthreads();
    // ---- compute: 2 x 128-K blocks, one scaled K=128 MFMA per (mi,ni) ----
#pragma unroll
    for (int kb = 0; kb < 2; ++kb) {
      i32x8 a8[4], b8[4];
#pragma unroll
      for (int mi = 0; mi < 4; ++mi) {
        int ar = wm * 64 + mi * 16 + lo;
        const char* rb = As + ar * 256 + kb * 128;
        int x = ar & 7;
        union { i32x8 v8; i32x4 v4[2]; } u;
        u.v4[0] = *(const i32x4*)(rb + ((hi * 2 + 0) ^ x) * 16);
        u.v4[1] = *(const i32x4*)(rb + ((hi * 2 + 1) ^ x) * 16);
        a8[mi] = u.v8;
      }
#pragma unroll
      for (int ni = 0; ni < 4; ++ni) {
        int br = wn * 64 + ni * 16 + lo;
        const char* rb = Bs + br * 256 + kb * 128;
        int x = br & 7;
        union { i32x8 v8; i32x4 v4[2]; } u;
        u.v4[0] = *(const i32x4*)(rb + ((hi * 2 + 0) ^ x) * 16);
        u.v4[1] = *(const i32x4*)(rb + ((hi * 2 + 1) ^ x) * 16);
        b8[ni] = u.v8;
      }
#pragma unroll
      for (int mi = 0; mi < 4; ++mi)
#pragma unroll
        for (int ni = 0; ni < 4; ++ni)
          acc[mi][ni] = __builtin_amdgcn_mfma_scale_f32_16x16x128_f8f6f4(
              a8[mi], b8[ni], acc[mi][ni], 0, 0, 0, 0x7F, 0, 0x7F);
    }
    __syncthreads();
  }

  // epilogue: bias, exp, per-row partial sums; capture target logit
#pragma unroll
  for (int mi = 0; mi < 4; ++mi) {
    int r0 = row0 + wm * 64 + mi * 16 + hi * 4;
    int tg[4];
    float s[4] = {0.f, 0.f, 0.f, 0.f};
#pragma unroll
    for (int j = 0; j < 4; ++j) tg[j] = tgt[r0 + j];
#pragma unroll
    for (int ni = 0; ni < 4; ++ni) {
      int col = col0 + wn * 64 + ni * 16 + lo;
      float bb = SB[col];
#pragma unroll
      for (int j = 0; j < 4; ++j) {
        float v = acc[mi][ni][j] + bb;
        if (col == tg[j]) TGL[r0 + j] = v;   // exactly one writer per row
        s[j] += __expf(v);
      }
    }
#pragma unroll
    for (int m = 1; m < 16; m <<= 1) {
#pragma unroll
      for (int j = 0; j < 4; ++j) s[j] += __shfl_xor(s[j], m, 64);
    }
    if (lo == 0) {
#pragma unroll
      for (int j = 0; j < 4; ++j) atomicAdd(&SUM[r0 + j], s[j]);
    }
  }
}

// ---------------- fo-pool scan (bf16 in; bf16 out mode 0, phys-K fp8 out mode 1) ----------------
__global__ __launch_bounds__(64) void scan_kernel(const ushort* __restrict__ PRE,
                                                  ushort* __restrict__ OUT16,
                                                  unsigned char* __restrict__ OUT8,
                                                  int mode) {
  int idx = blockIdx.x * 64 + threadIdx.x;    // 32*512
  int b = idx >> 9, d = idx & 511;
  const ushort* p = PRE + (size_t)b * TT * G3 + d;
  int poff = physk(d);
  float c = 0.f;
  for (int t0 = 0; t0 < TT; t0 += 8) {
    float pz[8], pf[8], po[8];
#pragma unroll
    for (int i = 0; i < 8; ++i) {
      const ushort* q = p + (size_t)(t0 + i) * G3;
      pz[i] = bf2f(q[0]); pf[i] = bf2f(q[512]); po[i] = bf2f(q[1024]);
    }
#pragma unroll
    for (int i = 0; i < 8; ++i) {
      float z = 2.f / (1.f + __expf(-2.f * pz[i])) - 1.f;
      float f = 1.f / (1.f + __expf(-pf[i]));
      float o = 1.f / (1.f + __expf(-po[i]));
      c = f * c + (1.f - f) * z;
      float h = o * c;
      int tt = t0 + i;
      size_t r = (size_t)b * TT + tt;
      if (mode == 0) {
        ushort hb = f2bf(h);
        OUT16[r * 1024 + 512 + d] = hb;
        if (tt < TT - 1) OUT16[(r + 1) * 1024 + d] = hb;
        if (tt == 0)     OUT16[r * 1024 + d] = 0;
      } else {
        OUT8[r * 512 + poff] = f2e4m3(h);
      }
    }
  }
}

// ---------------- helpers ----------------
__global__ void zero_kernel(float* __restrict__ p, int n) {
  int i = blockIdx.x * 256 + threadIdx.x;
  if (i < n) p[i] = 0.f;
}

__global__ __launch_bounds__(256) void cost_kernel(const float* __restrict__ sumexp,
                                                   const float* __restrict__ tgl,
                                                   float* __restrict__ out) {
  int t = threadIdx.x;
  float s = 0.f;
  for (int r = t; r < R; r += 256) s += logf(sumexp[r]) - tgl[r];
#pragma unroll
  for (int m = 1; m < 64; m <<= 1) s += __shfl_xor(s, m, 64);
  __shared__ float red[4];
  int wave = t >> 6, lane = t & 63;
  if (lane == 0) red[wave] = s;
  __syncthreads();
  if (t == 0) out[0] = (red[0] + red[1] + red[2] + red[3]) / (float)R;
}

extern "C" void kernel_launch(void* const* d_in, const int* in_sizes, int n_in,
                              void* d_out, int out_size, void* d_ws, size_t ws_size,
                              hipStream_t stream) {
  const int*   tok = (const int*)d_in[0];
  const int*   tgt = (const int*)d_in[1];
  const float* emb = (const float*)d_in[2];
  const float* Wz0 = (const float*)d_in[3];  const float* bz0 = (const float*)d_in[4];
  const float* Wf0 = (const float*)d_in[5];  const float* bf0 = (const float*)d_in[6];
  const float* Wo0 = (const float*)d_in[7];  const float* bo0 = (const float*)d_in[8];
  const float* Wz1 = (const float*)d_in[9];  const float* bz1 = (const float*)d_in[10];
  const float* Wf1 = (const float*)d_in[11]; const float* bf1 = (const float*)d_in[12];
  const float* Wo1 = (const float*)d_in[13]; const float* bo1 = (const float*)d_in[14];
  const float* SW  = (const float*)d_in[15]; const float* SB  = (const float*)d_in[16];
  float* out = (float*)d_out;

  // workspace layout (bytes):
  char* base = (char*)d_ws;
  ushort*        XA  = (ushort*)(base);               // 16,777,216  [R][1024] bf16
  ushort*        YA  = (ushort*)(base + 16777216);    // 16,777,216  [R][1024] bf16
  ushort*        PRE = (ushort*)(base + 33554432);    // 25,165,824  [R][1536] bf16
  unsigned char* H8  = (unsigned char*)(base + 58720256);  // 4,194,304 [R][512] fp8 phys-K
  ushort*        WT0 = (ushort*)(base + 67108864);    //  3,145,728  [1536][1024] bf16
  ushort*        WT1 = (ushort*)(base + 70254592);    //  3,145,728
  float*         BC0 = (float*)(base + 73400320);     //  6,144
  float*         BC1 = (float*)(base + 73406464);     //  6,144
  float*         SUM = (float*)(base + 73412608);     //  32,768
  float*         TGL = (float*)(base + 73445376);     //  32,768
  unsigned char* SW8T = (unsigned char*)(base);       // 16,384,000 — aliases XA (dead by then)

  embed_kernel<<<R * 128 / 256, 256, 0, stream>>>(tok, (const float4*)emb, (ushort4*)XA);
  wconv<<<dim3(8, 8, 6), 256, 0, stream>>>(Wz0, Wf0, Wo0, WT0);
  wconv<<<dim3(8, 8, 6), 256, 0, stream>>>(Wz1, Wf1, Wo1, WT1);
  bcat_kernel<<<12, 256, 0, stream>>>(bz0, bf0, bo0, bz1, bf1, bo1, BC0, BC1);

  gemm_pre<<<dim3(64, 12), 256, 0, stream>>>(XA, WT0, BC0, PRE);
  scan_kernel<<<256, 64, 0, stream>>>(PRE, YA, nullptr, 0);
  gemm_pre<<<dim3(64, 12), 256, 0, stream>>>(YA, WT1, BC1, PRE);
  scan_kernel<<<256, 64, 0, stream>>>(PRE, nullptr, H8, 1);

  // SW8T aliases XA — dead after the first gemm_pre
  swconv<<<dim3(8, 500), 256, 0, stream>>>(SW, SW8T);
  zero_kernel<<<32, 256, 0, stream>>>(SUM, R);
  gemm_lse_fp8<<<dim3(64, 250), 256, 0, stream>>>(H8, SW8T, SB, tgt, SUM, TGL);
  cost_kernel<<<1, 256, 0, stream>>>(SUM, TGL, out);
}